// Round 24
// baseline (511.848 us; speedup 1.0000x reference)
//
#include <hip/hip_runtime.h>
#include <math.h>

#define D_ 1024
#define H_ 16
#define HD_ 64
#define FF_ 4096
#define E_ 8
#define B_ 2
#define S_ 2048
#define T_ 4096
#define MAXROWS 9216
#define MAXTILES 72

typedef unsigned short u16;
typedef __attribute__((ext_vector_type(4))) float f32x4;
typedef __attribute__((ext_vector_type(8))) __bf16 bf16x8;
typedef __attribute__((ext_vector_type(8))) _Float16 f16x8;
typedef __attribute__((ext_vector_type(4))) unsigned short u16x4;

__device__ __forceinline__ u16 f2bf(float f){
  union { float f; unsigned u; } v; v.f = f;
  unsigned r = v.u + 0x7fffu + ((v.u >> 16) & 1u);
  return (u16)(r >> 16);
}
__device__ __forceinline__ float bf2f(u16 h){
  union { unsigned u; float f; } v; v.u = ((unsigned)h) << 16;
  return v.f;
}
__device__ __forceinline__ void glds16(const void* g, void* l){
  __builtin_amdgcn_global_load_lds((const __attribute__((address_space(1))) void*)g,
                                   (__attribute__((address_space(3))) void*)l, 16, 0, 0);
}
__device__ __forceinline__ bf16x8 ld8(const u16* p){
  return *reinterpret_cast<const bf16x8*>(p);
}
__device__ __forceinline__ f16x8 ldH8(const _Float16* p){
  return *reinterpret_cast<const f16x8*>(p);
}
__device__ __forceinline__ f32x4 mfma16(bf16x8 a, bf16x8 b, f32x4 c){
  return __builtin_amdgcn_mfma_f32_16x16x32_bf16(a, b, c, 0, 0, 0);
}
__device__ __forceinline__ f32x4 mfmaH(f16x8 a, f16x8 b, f32x4 c){
  return __builtin_amdgcn_mfma_f32_16x16x32_f16(a, b, c, 0, 0, 0);
}
__device__ __forceinline__ unsigned pk16(float a, float b){
  auto pk = __builtin_amdgcn_cvt_pkrtz(a, b);
  return __builtin_bit_cast(unsigned, pk);
}

// merged projection-weight conversion: ipw -> fp16, opw -> fp16 hi/lo.
__global__ void __launch_bounds__(256) cvt_wproj_kernel(
    const float* __restrict__ ipw, _Float16* __restrict__ wipf,
    const float* __restrict__ opw, _Float16* __restrict__ woph, _Float16* __restrict__ wopl,
    int n4a, int n4b)
{
  int i = blockIdx.x*blockDim.x + threadIdx.x;
  if (i < n4a){
    float4 v = reinterpret_cast<const float4*>(ipw)[i];
    union { unsigned w[2]; u16x4 u; } o;
    o.w[0] = pk16(v.x, v.y);
    o.w[1] = pk16(v.z, v.w);
    reinterpret_cast<u16x4*>(wipf)[i] = o.u;
  } else if (i < n4a + n4b){
    const int j = i - n4a;
    float4 v = reinterpret_cast<const float4*>(opw)[j];
    float vv[4] = {v.x, v.y, v.z, v.w};
    u16x4 h, l;
    #pragma unroll
    for (int k=0;k<4;k++){
      const _Float16 hh = (_Float16)vv[k];
      const _Float16 ll = (_Float16)(vv[k] - (float)hh);
      h[k] = __builtin_bit_cast(u16, hh);
      l[k] = __builtin_bit_cast(u16, ll);
    }
    reinterpret_cast<u16x4*>(woph)[j] = h;
    reinterpret_cast<u16x4*>(wopl)[j] = l;
  }
}

// OUTMODE 1: fp16 out; OUTMODE 2: bf16 out. GATE: fused MoE gate.
template<int OUTMODE, int GATE>
__global__ void __launch_bounds__(256) ln_kernel(const float* __restrict__ x, const float* __restrict__ g,
    const float* __restrict__ bta, float* __restrict__ outf, u16* __restrict__ nout,
    const float* __restrict__ gw, const float* __restrict__ gb,
    float* __restrict__ probs_out, int* __restrict__ top_i, float* __restrict__ cw_w)
{
  const int t = blockIdx.x, tid = threadIdx.x;
  __shared__ float rs[4], rq[4];
  __shared__ float sp[4][E_];
  const float4 v = reinterpret_cast<const float4*>(x + (size_t)t*D_)[tid];
  float s  = v.x+v.y+v.z+v.w;
  float s2 = v.x*v.x+v.y*v.y+v.z*v.z+v.w*v.w;
  #pragma unroll
  for (int o=32;o;o>>=1){ s += __shfl_xor(s,o); s2 += __shfl_xor(s2,o); }
  const int wid=tid>>6, lane=tid&63;
  if (lane==0){ rs[wid]=s; rq[wid]=s2; }
  __syncthreads();
  s  = rs[0]+rs[1]+rs[2]+rs[3];
  s2 = rq[0]+rq[1]+rq[2]+rq[3];
  const float mu  = s*(1.0f/D_);
  const float var = s2*(1.0f/D_) - mu*mu;
  const float inv = rsqrtf(var + 1e-5f);
  const float4 gv = reinterpret_cast<const float4*>(g)[tid];
  const float4 bv = reinterpret_cast<const float4*>(bta)[tid];
  float oo[4];
  oo[0] = (v.x-mu)*inv*gv.x + bv.x;
  oo[1] = (v.y-mu)*inv*gv.y + bv.y;
  oo[2] = (v.z-mu)*inv*gv.z + bv.z;
  oo[3] = (v.w-mu)*inv*gv.w + bv.w;
  const size_t base = (size_t)t*D_ + tid*4;
  if (outf){ outf[base]=oo[0]; outf[base+1]=oo[1]; outf[base+2]=oo[2]; outf[base+3]=oo[3]; }
  if (OUTMODE==1){
    union { unsigned w[2]; u16x4 u; } hv;
    hv.w[0] = pk16(oo[0], oo[1]);
    hv.w[1] = pk16(oo[2], oo[3]);
    reinterpret_cast<u16x4*>(nout)[base>>2] = hv.u;
  } else {
    u16x4 hv;
    hv[0]=f2bf(oo[0]); hv[1]=f2bf(oo[1]); hv[2]=f2bf(oo[2]); hv[3]=f2bf(oo[3]);
    reinterpret_cast<u16x4*>(nout)[base>>2] = hv;
  }
  if (GATE){
    float part[E_];
    #pragma unroll
    for (int e=0;e<E_;e++){
      const float4 wv = reinterpret_cast<const float4*>(gw + (size_t)e*D_)[tid];
      part[e] = oo[0]*wv.x + oo[1]*wv.y + oo[2]*wv.z + oo[3]*wv.w;
    }
    #pragma unroll
    for (int e=0;e<E_;e++){
      #pragma unroll
      for (int o=32;o;o>>=1) part[e] += __shfl_xor(part[e], o);
    }
    if (lane==0){
      #pragma unroll
      for (int e=0;e<E_;e++) sp[wid][e] = part[e];
    }
    __syncthreads();
    if (tid==0){
      float lg[E_], mx=-3e38f;
      #pragma unroll
      for (int e=0;e<E_;e++){
        lg[e] = sp[0][e]+sp[1][e]+sp[2][e]+sp[3][e] + gb[e];
        mx = fmaxf(mx, lg[e]);
      }
      float ex[E_], sm=0.f;
      #pragma unroll
      for (int e=0;e<E_;e++){ ex[e]=__expf(lg[e]-mx); sm+=ex[e]; }
      float p[E_];
      #pragma unroll
      for (int e=0;e<E_;e++){ p[e]=ex[e]/sm; probs_out[(size_t)t*E_+e]=p[e]; }
      int i0=0; float l0=lg[0];
      #pragma unroll
      for (int e=1;e<E_;e++) if (lg[e]>l0){ l0=lg[e]; i0=e; }
      int i1=-1; float l1=-3e38f;
      #pragma unroll
      for (int e=0;e<E_;e++) if (e!=i0 && lg[e]>l1){ l1=lg[e]; i1=e; }
      top_i[2*t]=i0; top_i[2*t+1]=i1;
      const float v0=p[i0], v1=p[i1];
      const float swt=v0+v1;
      cw_w[2*t]=v0/swt; cw_w[2*t+1]=v1/swt;
    }
  }
}

// fp16 single-product QKV GEMM, LDS dbuf + counted vmcnt(4) pipeline,
// XCD-chunked 1D grid. NT = 24.
__global__ void __launch_bounds__(256) qkv_kernel(
    const _Float16* __restrict__ A, const _Float16* __restrict__ Bw,
    const float* __restrict__ bias,
    _Float16* __restrict__ qf, _Float16* __restrict__ kf, _Float16* __restrict__ vtf)
{
  __shared__ __align__(16) _Float16 Ash[2][128*32], Bsh[2][128*32];
  const int bid = blockIdx.x, nwg = gridDim.x;
  const int fid = (bid & 7)*(nwg>>3) + (bid>>3);
  const int nt = fid % 24, mt = fid / 24;
  const int tid=threadIdx.x, wid=tid>>6, lane=tid&63;
  const int wr=wid>>1, wc=wid&1;
  const int r16=lane&15, g4=lane>>4;
  const _Float16* Ag = A  + (size_t)mt*128*D_;
  const _Float16* Bg = Bw + (size_t)nt*128*D_;
  const int srow = wid*16 + (lane>>2);
  const int scol = (((lane&3) ^ ((lane>>3)&3)))*8;
  const int sl   = (g4 ^ ((r16>>1)&3))*8;
  f32x4 acc[4][4] = {};
#define QSTAGE(bi, k0) do { \
    _Pragma("unroll") \
    for (int p=0;p<2;p++){ \
      const int r  = p*64 + srow; \
      const int lo = (p*64 + wid*16)*32; \
      glds16(Ag + (size_t)r*D_ + (k0) + scol, &Ash[bi][lo]); \
      glds16(Bg + (size_t)r*D_ + (k0) + scol, &Bsh[bi][lo]); \
    } \
  } while(0)
  QSTAGE(0, 0);
  int cur = 0;
  for (int t=0; t<D_/32; ++t){
    if (t+1 < D_/32){
      QSTAGE(cur^1, (t+1)*32);
      asm volatile("s_waitcnt vmcnt(4)" ::: "memory");
    } else {
      asm volatile("s_waitcnt vmcnt(0)" ::: "memory");
    }
    __syncthreads();
    f16x8 af[4], bfr[4];
    #pragma unroll
    for (int m=0;m<4;m++) af[m]=ldH8(&Ash[cur][(wr*64+m*16+r16)*32 + sl]);
    #pragma unroll
    for (int n=0;n<4;n++) bfr[n]=ldH8(&Bsh[cur][(wc*64+n*16+r16)*32 + sl]);
    #pragma unroll
    for (int m=0;m<4;m++){
      #pragma unroll
      for (int n=0;n<4;n++) acc[m][n] = mfmaH(af[m], bfr[n], acc[m][n]);
    }
    __syncthreads();
    cur ^= 1;
  }
#undef QSTAGE
  #pragma unroll
  for (int m=0;m<4;m++){
    #pragma unroll
    for (int n=0;n<4;n++){
      #pragma unroll
      for (int r=0;r<4;r++){
        const int grow = mt*128 + wr*64 + m*16 + g4*4 + r;
        const int gcol = nt*128 + wc*64 + n*16 + r16;
        const float val = acc[m][n][r] + bias[gcol];
        const int which = gcol>>10, rem = gcol&1023;
        const int hh = rem>>6, ee = rem&63;
        const int bb = grow>>11, ss = grow&2047;
        if (which==0){
          qf[((size_t)(bb*H_+hh)*S_ + ss)*HD_ + ee] = (_Float16)(val * 0.18033688f);
        } else if (which==1){
          kf[((size_t)(bb*H_+hh)*S_ + ss)*HD_ + ee] = (_Float16)val;
        } else {
          const int p32 = 2*(ss & 12) + (ss & 3) + 4*((ss >> 4) & 1);
          const size_t idx = (((size_t)(bb*H_+hh)*(S_/32) + (ss>>5))*HD_ + ee)*32 + p32;
          vtf[idx] = (_Float16)val;
        }
      }
    }
  }
}

// out-proj GEMM: A = attn output (fp16 single), B = opw (fp16 hi/lo).
// 2-product fp32-equivalent. LDS dbuf (3 buffers) + vmcnt(6), XCD-chunked.
__global__ void __launch_bounds__(256) gemm3_kernel(
    const _Float16* __restrict__ A, int lda,
    const _Float16* __restrict__ Bh, const _Float16* __restrict__ Bl, int Kdim,
    const float* __restrict__ bias,
    const float* __restrict__ resid, float* __restrict__ x1out)
{
  __shared__ __align__(16) _Float16 Ash[2][128*32], Bsh[2][128*32], Bsl[2][128*32];
  const int bid = blockIdx.x, nwg = gridDim.x;
  const int fid = (bid & 7)*(nwg>>3) + (bid>>3);
  const int nt = fid & 7, mt = fid >> 3;
  const int tid=threadIdx.x, wid=tid>>6, lane=tid&63;
  const int wr=wid>>1, wc=wid&1;
  const int r16=lane&15, g4=lane>>4;
  const _Float16* Ag  = A  + (size_t)mt*128*lda;
  const _Float16* Bgh = Bh + (size_t)nt*128*Kdim;
  const _Float16* Bgl = Bl + (size_t)nt*128*Kdim;
  const int srow = wid*16 + (lane>>2);
  const int scol = (((lane&3) ^ ((lane>>3)&3)))*8;
  const int sl   = (g4 ^ ((r16>>1)&3))*8;
  f32x4 acc[4][4] = {};
#define G3STAGE(bi, k0) do { \
    _Pragma("unroll") \
    for (int p=0;p<2;p++){ \
      const int r  = p*64 + srow; \
      const int lo = (p*64 + wid*16)*32; \
      glds16(Ag  + (size_t)r*lda  + (k0) + scol, &Ash[bi][lo]); \
      glds16(Bgh + (size_t)r*Kdim + (k0) + scol, &Bsh[bi][lo]); \
      glds16(Bgl + (size_t)r*Kdim + (k0) + scol, &Bsl[bi][lo]); \
    } \
  } while(0)
  G3STAGE(0, 0);
  int cur = 0;
  const int NK = Kdim/32;
  for (int t=0; t<NK; ++t){
    if (t+1 < NK){
      G3STAGE(cur^1, (t+1)*32);
      asm volatile("s_waitcnt vmcnt(6)" ::: "memory");
    } else {
      asm volatile("s_waitcnt vmcnt(0)" ::: "memory");
    }
    __syncthreads();
    f16x8 af[4], bfh[4], bfl[4];
    #pragma unroll
    for (int m=0;m<4;m++){
      const int row = wr*64 + m*16 + r16;
      af[m] = ldH8(&Ash[cur][row*32 + sl]);
    }
    #pragma unroll
    for (int n=0;n<4;n++){
      const int row = wc*64 + n*16 + r16;
      bfh[n] = ldH8(&Bsh[cur][row*32 + sl]);
      bfl[n] = ldH8(&Bsl[cur][row*32 + sl]);
    }
    #pragma unroll
    for (int m=0;m<4;m++){
      #pragma unroll
      for (int n=0;n<4;n++){
        acc[m][n] = mfmaH(af[m], bfl[n], acc[m][n]);
        acc[m][n] = mfmaH(af[m], bfh[n], acc[m][n]);
      }
    }
    __syncthreads();
    cur ^= 1;
  }
#undef G3STAGE
  #pragma unroll
  for (int m=0;m<4;m++){
    #pragma unroll
    for (int n=0;n<4;n++){
      #pragma unroll
      for (int r=0;r<4;r++){
        const int grow = mt*128 + wr*64 + m*16 + g4*4 + r;
        const int gcol = nt*128 + wc*64 + n*16 + r16;
        const float val = acc[m][n][r] + bias[gcol];
        const size_t idx = (size_t)grow*D_ + gcol;
        x1out[idx] = val + resid[idx];
      }
    }
  }
}

// fp16 flash attention v10, standalone (R19 measured config): 512 blocks x
// 512 threads / 8 waves, 128 q-rows/block, KVBLK=64, dbuf + vmcnt(2).
__global__ void __launch_bounds__(512, 2) attn10_kernel(
    const _Float16* __restrict__ Qf, const _Float16* __restrict__ Kf,
    const _Float16* __restrict__ Vtf,
    _Float16* __restrict__ Of)
{
  __shared__ __align__(16) _Float16 Kb[2][4096];
  __shared__ __align__(16) _Float16 Vb[2][4096];
  const int bid = blockIdx.x;
  const int wg = (bid & 7) * 64 + (bid >> 3);
  const int bh = wg >> 4, qc = wg & 15;
  const int tid=threadIdx.x, wid=tid>>6, lane=tid&63;
  const int r16=lane&15, g4=lane>>4;
  const int q0 = qc*128 + wid*16;
  const _Float16* Qp = Qf  + (size_t)bh*S_*HD_ + (size_t)(q0+r16)*HD_ + g4*8;
  const _Float16* Kbase = Kf  + (size_t)bh*S_*HD_;
  const _Float16* Vbase = Vtf + (size_t)bh*HD_*S_;
  const f16x8 qf0 = ldH8(Qp);
  const f16x8 qf1 = ldH8(Qp+32);
  f32x4 of[4] = {};
  float m_run = -3e38f, lr = 0.f;

  const int kOff = (wid*8 + (lane>>3))*HD_ + (((lane&7) ^ ((lane>>3)&7)))*8;
  const int vOff = wid*512 + lane*8;
  const int sk0 = (g4 ^ (r16&7))*8;
  const int sk1 = ((g4+4) ^ (r16&7))*8;

#define STAGE(bi, tt) do { \
    glds16(Kbase + (size_t)(tt)*64*HD_ + kOff, (void*)&Kb[bi][wid*512]); \
    glds16(Vbase + (size_t)(tt)*4096   + vOff, (void*)&Vb[bi][wid*512]); \
  } while(0)

#define ATT_HALF(Kh_, Vh_) do { \
    const f16x8 k0v = ldH8((Kh_) + r16*64 + sk0); \
    const f16x8 k1v = ldH8((Kh_) + r16*64 + sk1); \
    const f16x8 k2v = ldH8((Kh_) + (16+r16)*64 + sk0); \
    const f16x8 k3v = ldH8((Kh_) + (16+r16)*64 + sk1); \
    f32x4 sA={}, sB={}; \
    __builtin_amdgcn_s_setprio(1); \
    sA = mfmaH(k0v, qf0, sA); sA = mfmaH(k1v, qf1, sA); \
    sB = mfmaH(k2v, qf0, sB); sB = mfmaH(k3v, qf1, sB); \
    __builtin_amdgcn_s_setprio(0); \
    const float t0=sA[0], t1=sA[1], t2=sA[2], t3=sA[3]; \
    const float t4=sB[0], t5=sB[1], t6=sB[2], t7=sB[3]; \
    const float lmx = fmaxf(fmaxf(fmaxf(t0,t1),fmaxf(t2,t3)), \
                            fmaxf(fmaxf(t4,t5),fmaxf(t6,t7))); \
    if (!__all(lmx <= m_run + 4.0f)) { \
      float mx = fmaxf(lmx, __shfl_xor(lmx,16)); \
      mx = fmaxf(mx, __shfl_xor(mx,32)); \
      const float mn = fmaxf(m_run, mx); \
      const float alp = __builtin_amdgcn_exp2f(m_run - mn); \
      m_run = mn; \
      lr *= alp; \
      const float ao0=__shfl(alp,4*g4), ao1=__shfl(alp,4*g4+1); \
      const float ao2=__shfl(alp,4*g4+2), ao3=__shfl(alp,4*g4+3); \
      _Pragma("unroll") \
      for (int c=0;c<4;c++){ of[c][0]*=ao0; of[c][1]*=ao1; of[c][2]*=ao2; of[c][3]*=ao3; } \
    } \
    const float msh = m_run - 9.0f; \
    const float p0=__builtin_amdgcn_exp2f(t0-msh), p1=__builtin_amdgcn_exp2f(t1-msh); \
    const float p2=__builtin_amdgcn_exp2f(t2-msh), p3=__builtin_amdgcn_exp2f(t3-msh); \
    const float p4=__builtin_amdgcn_exp2f(t4-msh), p5=__builtin_amdgcn_exp2f(t5-msh); \
    const float p6=__builtin_amdgcn_exp2f(t6-msh), p7=__builtin_amdgcn_exp2f(t7-msh); \
    lr += ((p0+p1)+(p2+p3)) + ((p4+p5)+(p6+p7)); \
    union { unsigned w[4]; f16x8 v; } pu; \
    pu.w[0]=pk16(p0,p1); pu.w[1]=pk16(p2,p3); \
    pu.w[2]=pk16(p4,p5); pu.w[3]=pk16(p6,p7); \
    const f16x8 v0v = ldH8((Vh_) + (r16)*32 + g4*8); \
    const f16x8 v1v = ldH8((Vh_) + (16+r16)*32 + g4*8); \
    const f16x8 v2v = ldH8((Vh_) + (32+r16)*32 + g4*8); \
    const f16x8 v3v = ldH8((Vh_) + (48+r16)*32 + g4*8); \
    __builtin_amdgcn_s_setprio(1); \
    of[0] = mfmaH(pu.v, v0v, of[0]); of[1] = mfmaH(pu.v, v1v, of[1]); \
    of[2] = mfmaH(pu.v, v2v, of[2]); of[3] = mfmaH(pu.v, v3v, of[3]); \
    __builtin_amdgcn_s_setprio(0); \
  } while(0)

  STAGE(0, 0);
  int cur = 0;

  for (int t=0; t<32; ++t){
    if (t < 31){
      STAGE(cur^1, t+1);
      asm volatile("s_waitcnt vmcnt(2)" ::: "memory");
    } else {
      asm volatile("s_waitcnt vmcnt(0)" ::: "memory");
    }
    __syncthreads();
    ATT_HALF(&Kb[cur][0],    &Vb[cur][0]);
    ATT_HALF(&Kb[cur][2048], &Vb[cur][2048]);
    __syncthreads();
    cur ^= 1;
  }
#undef ATT_HALF
#undef STAGE

  lr += __shfl_xor(lr,16);
  lr += __shfl_xor(lr,32);
  float li[4];
  #pragma unroll
  for (int r=0;r<4;r++) li[r] = 1.0f / __shfl(lr, 4*g4+r);
  const int bb = bh>>4, hh = bh&15;
  #pragma unroll
  for (int c=0;c<4;c++){
    #pragma unroll
    for (int r=0;r<4;r++){
      const float val = of[c][r] * li[r];
      const int qq = q0 + 4*g4 + r;
      const size_t idx = ((size_t)(bb*S_+qq))*D_ + hh*HD_ + c*16 + r16;
      Of[idx] = (_Float16)val;
    }
  }
}

// routing scan + fused load-balance loss (1 block, 512 threads).
__global__ void __launch_bounds__(512) scan_kernel(const int* __restrict__ top_i,
    int* __restrict__ goff, int* __restrict__ tile_expert,
    int* __restrict__ assign_token, int* __restrict__ pos_of,
    const float* __restrict__ probs, float* __restrict__ loss_out)
{
  __shared__ int cnt[E_];
  __shared__ int off[E_+1];
  __shared__ float sf[8][E_], sP[8][E_];
  const int tid=threadIdx.x;
  if (tid<E_) cnt[tid]=0;
  __syncthreads();
  for (int t=tid;t<T_;t+=512){
    atomicAdd(&cnt[top_i[2*t]],1);
    atomicAdd(&cnt[top_i[2*t+1]],1);
  }
  __syncthreads();
  if (tid==0){
    off[0]=0;
    for (int e=0;e<E_;e++) off[e+1]=off[e]+((cnt[e]+127)&~127);
    for (int i=0;i<=E_;i++) goff[i]=off[i];
  }
  __syncthreads();
  if (tid<MAXTILES){
    const int r=tid*128; int e=-1;
    for (int j=0;j<E_;j++) if (r>=off[j] && r<off[j+1]) e=j;
    tile_expert[tid]=e;
  }
  const int lane=tid&63;
  const int e=tid>>6;
  int base=off[e];
  for (int c=0;c<T_/64;c++){
    const int t=c*64+lane;
    const int a0=top_i[2*t], a1=top_i[2*t+1];
    const bool f=(a0==e)||(a1==e);
    const unsigned long long m=__ballot(f);
    if (f){
      const int pos = base + (int)__popcll(m & ((1ull<<lane)-1ull));
      assign_token[pos]=t;
      pos_of[2*t + (a0==e?0:1)] = pos;
    }
    base += (int)__popcll(m);
  }
  for (int r=base+lane; r<off[e+1]; r+=64) assign_token[r]=-1;
  __syncthreads();
  for (int r=off[E_]+tid; r<MAXROWS; r+=512) assign_token[r]=-1;
  // ---- fused load-balance loss ----
  float fc[E_]={0,0,0,0,0,0,0,0}, Ps[E_]={0,0,0,0,0,0,0,0};
  for (int t=tid;t<T_;t+=512){
    const float* pr = probs + (size_t)t*E_;
    const int a0 = top_i[2*t];
    #pragma unroll
    for (int k=0;k<E_;k++){
      Ps[k] += pr[k];
      fc[k] += (a0==k) ? 1.0f : 0.0f;
    }
  }
  #pragma unroll
  for (int k=0;k<E_;k++){
    #pragma unroll
    for (int o=32;o;o>>=1){ fc[k]+=__shfl_xor(fc[k],o); Ps[k]+=__shfl_xor(Ps[k],o); }
  }
  const int wid8 = tid>>6;
  if (lane==0){
    #pragma unroll
    for (int k=0;k<E_;k++){ sf[wid8][k]=fc[k]; sP[wid8][k]=Ps[k]; }
  }
  __syncthreads();
  if (tid==0){
    float loss=0.f;
    #pragma unroll
    for (int k=0;k<E_;k++){
      float fe=0.f, Pe=0.f;
      #pragma unroll
      for (int w=0;w<8;w++){ fe+=sf[w][k]; Pe+=sP[w][k]; }
      loss += (fe/(float)T_)*(Pe/(float)T_);
    }
    loss_out[0] = 0.01f*(float)E_*loss;
  }
}

// grouped GEMM, bf16 A (LDS) x fp32 B (LDS, staged raw from HBM, converted
// to bf16 fragments in-register via v_cvt_pk_bf16_f32). Eliminates the
// standalone w1/w2 bf16 conversion pass (603 MB HBM) — gemm_grp has idle BW.
// B LDS layout: [128 rows][8 granules of 16B], granule p of row r holds
// global granule p^(r&7) (both-sides XOR swizzle, same family as bf16 path).
// MODE 2: FFN1 + tanh-GELU, A gathered via atok. MODE 3: FFN2, dense A.
template<int MODE>
__global__ void __launch_bounds__(256, 3) gemm_grp_kernel(
    const u16* __restrict__ A, int lda,
    const float* __restrict__ Bbase, int Kdim, int Nsz, int NT,
    const float* __restrict__ bias,
    const int* __restrict__ tile_expert,
    const int* __restrict__ atok,
    u16* __restrict__ outp)
{
  const int bid = blockIdx.x, nwg = gridDim.x;
  const int fid = (bid & 7)*(nwg>>3) + (bid>>3);
  const int nt = fid % NT, mt = fid / NT;
  const int e = tile_expert[mt];
  if (e<0) return;
  __shared__ __align__(16) u16 Ash[2][128*32];
  __shared__ __align__(16) float Bsh32[2][128*32];
  const int tid=threadIdx.x, wid=tid>>6, lane=tid&63;
  const int wr=wid>>1, wc=wid&1;
  const int r16=lane&15, g4=lane>>4;
  const float* bp = bias + (size_t)e*Nsz;
  const int srow = wid*16 + (lane>>2);
  const int scol = (((lane&3) ^ ((lane>>3)&3)))*8;
  const int sl   = (g4 ^ ((r16>>1)&3))*8;
  const float* Bg = Bbase + (size_t)e*Nsz*Kdim + (size_t)nt*128*Kdim;
  size_t arow0, arow1;
  if (MODE==2){
    int t0 = atok[mt*128 + srow];      if (t0 < 0) t0 = 0;
    int t1 = atok[mt*128 + 64 + srow]; if (t1 < 0) t1 = 0;
    arow0 = (size_t)t0*lda;
    arow1 = (size_t)t1*lda;
  } else {
    arow0 = (size_t)(mt*128 + srow)*lda;
    arow1 = (size_t)(mt*128 + 64 + srow)*lda;
  }
  f32x4 acc[4][4] = {};
  // B stage indices (4 glds16/thread/K-step): LDS granule G = i*256+tid,
  // row = G>>3, pos = G&7, source granule = pos ^ (row&7).
#define GSTAGE(bi, k0) do { \
    glds16(A + arow0 + (k0) + scol, &Ash[bi][(wid*16)*32]); \
    glds16(A + arow1 + (k0) + scol, &Ash[bi][(64 + wid*16)*32]); \
    _Pragma("unroll") \
    for (int i2=0;i2<4;i2++){ \
      const int G  = i2*256 + tid; \
      const int br = G>>3, bpp = G&7; \
      const int sg = bpp ^ (br&7); \
      glds16(Bg + (size_t)br*Kdim + (k0) + sg*4, &Bsh32[bi][(size_t)G*4]); \
    } \
  } while(0)
  GSTAGE(0, 0);
  int cur = 0;
  const int NK = Kdim/32;
  for (int t=0; t<NK; ++t){
    if (t+1 < NK){
      GSTAGE(cur^1, (t+1)*32);
      asm volatile("s_waitcnt vmcnt(6)" ::: "memory");
    } else {
      asm volatile("s_waitcnt vmcnt(0)" ::: "memory");
    }
    __syncthreads();
    bf16x8 af[4], bfr[4];
    #pragma unroll
    for (int m=0;m<4;m++) af[m]=ld8(&Ash[cur][(wr*64+m*16+r16)*32 + sl]);
    #pragma unroll
    for (int n=0;n<4;n++){
      const int row = wc*64 + n*16 + r16;
      const int p0 = (2*g4)   ^ (r16&7);
      const int p1 = (2*g4+1) ^ (r16&7);
      const f32x4 x0 = *reinterpret_cast<const f32x4*>(&Bsh32[cur][row*32 + p0*4]);
      const f32x4 x1 = *reinterpret_cast<const f32x4*>(&Bsh32[cur][row*32 + p1*4]);
      union { unsigned w[4]; bf16x8 v; } u;
      asm("v_cvt_pk_bf16_f32 %0, %1, %2" : "=v"(u.w[0]) : "v"(x0[0]), "v"(x0[1]));
      asm("v_cvt_pk_bf16_f32 %0, %1, %2" : "=v"(u.w[1]) : "v"(x0[2]), "v"(x0[3]));
      asm("v_cvt_pk_bf16_f32 %0, %1, %2" : "=v"(u.w[2]) : "v"(x1[0]), "v"(x1[1]));
      asm("v_cvt_pk_bf16_f32 %0, %1, %2" : "=v"(u.w[3]) : "v"(x1[2]), "v"(x1[3]));
      bfr[n] = u.v;
    }
    #pragma unroll
    for (int m=0;m<4;m++){
      #pragma unroll
      for (int n=0;n<4;n++) acc[m][n] = mfma16(af[m], bfr[n], acc[m][n]);
    }
    __syncthreads();
    cur ^= 1;
  }
#undef GSTAGE
  #pragma unroll
  for (int m=0;m<4;m++){
    #pragma unroll
    for (int n=0;n<4;n++){
      #pragma unroll
      for (int r=0;r<4;r++){
        const int grow = mt*128 + wr*64 + m*16 + g4*4 + r;
        const int gcol = nt*128 + wc*64 + n*16 + r16;
        float val = acc[m][n][r] + bp[gcol];
        if (MODE==2){
          const float z = val*(1.0f + 0.044715f*val*val)*2.3021622f;
          val = val / (1.0f + __builtin_amdgcn_exp2f(-z));
        }
        outp[(size_t)grow*Nsz + gcol] = f2bf(val);
      }
    }
  }
}

__global__ void __launch_bounds__(256) combine_kernel(const float* __restrict__ x1,
    const u16* __restrict__ eo, const int* __restrict__ pos_of, const float* __restrict__ cw_w,
    float* __restrict__ out0)
{
  const int t=blockIdx.x, tid=threadIdx.x;
  const int r0=pos_of[2*t], r1=pos_of[2*t+1];
  const float w0=cw_w[2*t], w1=cw_w[2*t+1];
  const u16x4 e0 = reinterpret_cast<const u16x4*>(eo + (size_t)r0*D_)[tid];
  const u16x4 e1 = reinterpret_cast<const u16x4*>(eo + (size_t)r1*D_)[tid];
  const float4 xv = reinterpret_cast<const float4*>(x1 + (size_t)t*D_)[tid];
  float4 o;
  o.x = xv.x + w0*bf2f(e0[0]) + w1*bf2f(e1[0]);
  o.y = xv.y + w0*bf2f(e0[1]) + w1*bf2f(e1[1]);
  o.z = xv.z + w0*bf2f(e0[2]) + w1*bf2f(e1[2]);
  o.w = xv.w + w0*bf2f(e0[3]) + w1*bf2f(e1[3]);
  reinterpret_cast<float4*>(out0 + (size_t)t*D_)[tid] = o;
}

static inline size_t alup(size_t x){ return (x+255)&~(size_t)255; }

extern "C" void kernel_launch(void* const* d_in, const int* in_sizes, int n_in,
                              void* d_out, int out_size, void* d_ws, size_t ws_size,
                              hipStream_t stream) {
  (void)in_sizes; (void)n_in; (void)out_size; (void)ws_size;
  const float* x    = (const float*)d_in[0];
  const float* ipw  = (const float*)d_in[1];
  const float* ipb  = (const float*)d_in[2];
  const float* opw  = (const float*)d_in[3];
  const float* opb  = (const float*)d_in[4];
  const float* ln1g = (const float*)d_in[5];
  const float* ln1b = (const float*)d_in[6];
  const float* ln2g = (const float*)d_in[7];
  const float* ln2b = (const float*)d_in[8];
  const float* gw   = (const float*)d_in[9];
  const float* gb   = (const float*)d_in[10];
  const float* w1   = (const float*)d_in[11];
  const float* b1   = (const float*)d_in[12];
  const float* w2   = (const float*)d_in[13];
  const float* b2   = (const float*)d_in[14];

  float* out0       = (float*)d_out;
  float* loss_out   = out0 + (size_t)T_*D_;
  float* probs_out  = loss_out + 1;
  float* normed_out = probs_out + (size_t)T_*E_;

  char* p = (char*)d_ws;
  auto take = [&](size_t bytes)->void*{ void* r = (void*)p; p += alup(bytes); return r; };

  _Float16* wipf  = (_Float16*)take((size_t)3*D_*D_*2);
  _Float16* wophf = (_Float16*)take((size_t)D_*D_*2);
  _Float16* woplf = (_Float16*)take((size_t)D_*D_*2);
  _Float16* nf16 = (_Float16*)take((size_t)T_*D_*2);
  _Float16* qf  = (_Float16*)take((size_t)T_*D_*2);
  _Float16* kf  = (_Float16*)take((size_t)T_*D_*2);
  _Float16* vtf = (_Float16*)take((size_t)T_*D_*2);
  _Float16* of16 = (_Float16*)take((size_t)T_*D_*2);
  float* x1  = (float*)take((size_t)T_*D_*4);
  u16* n2b   = (u16*)take((size_t)T_*D_*2);
  u16* hbuf  = (u16*)take((size_t)MAXROWS*FF_*2);
  u16* eo    = (u16*)take((size_t)MAXROWS*D_*2);
  int* top_i = (int*)take((size_t)T_*2*4);
  float* cww = (float*)take((size_t)T_*2*4);
  int* posof = (int*)take((size_t)T_*2*4);
  int* goff  = (int*)take((size_t)(E_+1)*4);
  int* texp  = (int*)take((size_t)MAXTILES*4);
  int* atok  = (int*)take((size_t)MAXROWS*4);

  cvt_wproj_kernel<<<(3*D_*D_/4 + D_*D_/4 + 255)/256, 256, 0, stream>>>(
      ipw, wipf, opw, wophf, woplf, 3*D_*D_/4, D_*D_/4);

  ln_kernel<1,0><<<T_, 256, 0, stream>>>(x, ln1g, ln1b, normed_out, (u16*)nf16,
                                         nullptr, nullptr, nullptr, nullptr, nullptr);

  qkv_kernel<<<dim3(24*(T_/128)), 256, 0, stream>>>(nf16, wipf, ipb, qf, kf, vtf);

  attn10_kernel<<<B_*H_*(S_/128), 512, 0, stream>>>(qf, kf, vtf, of16);

  gemm3_kernel<<<dim3(8*(T_/128)), 256, 0, stream>>>(
      of16, D_, wophf, woplf, D_, opb, x, x1);

  ln_kernel<2,1><<<T_, 256, 0, stream>>>(x1, ln2g, ln2b, nullptr, n2b,
                                         gw, gb, probs_out, top_i, cww);

  scan_kernel<<<1, 512, 0, stream>>>(top_i, goff, texp, atok, posof, probs_out, loss_out);

  gemm_grp_kernel<2><<<dim3((FF_/128)*MAXTILES), 256, 0, stream>>>(n2b, D_, w1, D_, FF_, FF_/128, b1, texp, atok, hbuf);
  gemm_grp_kernel<3><<<dim3((D_/128)*MAXTILES), 256, 0, stream>>>(hbuf, FF_, w2, FF_, D_, D_/128, b2, texp, nullptr, eo);

  combine_kernel<<<T_, 256, 0, stream>>>(x1, eo, posof, cww, out0);
}

// Round 25
// 494.168 us; speedup vs baseline: 1.0358x; 1.0358x over previous
//
#include <hip/hip_runtime.h>
#include <math.h>

#define D_ 1024
#define H_ 16
#define HD_ 64
#define FF_ 4096
#define E_ 8
#define B_ 2
#define S_ 2048
#define T_ 4096
#define MAXROWS 9216
#define MAXTILES 72
#define ATTNB 512
#define CVTB 512

typedef unsigned short u16;
typedef __attribute__((ext_vector_type(4))) float f32x4;
typedef __attribute__((ext_vector_type(8))) __bf16 bf16x8;
typedef __attribute__((ext_vector_type(8))) _Float16 f16x8;
typedef __attribute__((ext_vector_type(4))) unsigned short u16x4;

__device__ __forceinline__ u16 f2bf(float f){
  union { float f; unsigned u; } v; v.f = f;
  unsigned r = v.u + 0x7fffu + ((v.u >> 16) & 1u);
  return (u16)(r >> 16);
}
__device__ __forceinline__ float bf2f(u16 h){
  union { unsigned u; float f; } v; v.u = ((unsigned)h) << 16;
  return v.f;
}
__device__ __forceinline__ void glds16(const void* g, void* l){
  __builtin_amdgcn_global_load_lds((const __attribute__((address_space(1))) void*)g,
                                   (__attribute__((address_space(3))) void*)l, 16, 0, 0);
}
__device__ __forceinline__ bf16x8 ld8(const u16* p){
  return *reinterpret_cast<const bf16x8*>(p);
}
__device__ __forceinline__ f16x8 ldH8(const _Float16* p){
  return *reinterpret_cast<const f16x8*>(p);
}
__device__ __forceinline__ f32x4 mfma16(bf16x8 a, bf16x8 b, f32x4 c){
  return __builtin_amdgcn_mfma_f32_16x16x32_bf16(a, b, c, 0, 0, 0);
}
__device__ __forceinline__ f32x4 mfmaH(f16x8 a, f16x8 b, f32x4 c){
  return __builtin_amdgcn_mfma_f32_16x16x32_f16(a, b, c, 0, 0, 0);
}
__device__ __forceinline__ unsigned pk16(float a, float b){
  auto pk = __builtin_amdgcn_cvt_pkrtz(a, b);
  return __builtin_bit_cast(unsigned, pk);
}

// merged projection-weight conversion: ipw -> fp16, opw -> fp16 hi/lo.
__global__ void __launch_bounds__(256) cvt_wproj_kernel(
    const float* __restrict__ ipw, _Float16* __restrict__ wipf,
    const float* __restrict__ opw, _Float16* __restrict__ woph, _Float16* __restrict__ wopl,
    int n4a, int n4b)
{
  int i = blockIdx.x*blockDim.x + threadIdx.x;
  if (i < n4a){
    float4 v = reinterpret_cast<const float4*>(ipw)[i];
    union { unsigned w[2]; u16x4 u; } o;
    o.w[0] = pk16(v.x, v.y);
    o.w[1] = pk16(v.z, v.w);
    reinterpret_cast<u16x4*>(wipf)[i] = o.u;
  } else if (i < n4a + n4b){
    const int j = i - n4a;
    float4 v = reinterpret_cast<const float4*>(opw)[j];
    float vv[4] = {v.x, v.y, v.z, v.w};
    u16x4 h, l;
    #pragma unroll
    for (int k=0;k<4;k++){
      const _Float16 hh = (_Float16)vv[k];
      const _Float16 ll = (_Float16)(vv[k] - (float)hh);
      h[k] = __builtin_bit_cast(u16, hh);
      l[k] = __builtin_bit_cast(u16, ll);
    }
    reinterpret_cast<u16x4*>(woph)[j] = h;
    reinterpret_cast<u16x4*>(wopl)[j] = l;
  }
}

// OUTMODE 1: fp16 out; OUTMODE 2: bf16 out. GATE: fused MoE gate.
template<int OUTMODE, int GATE>
__global__ void __launch_bounds__(256) ln_kernel(const float* __restrict__ x, const float* __restrict__ g,
    const float* __restrict__ bta, float* __restrict__ outf, u16* __restrict__ nout,
    const float* __restrict__ gw, const float* __restrict__ gb,
    float* __restrict__ probs_out, int* __restrict__ top_i, float* __restrict__ cw_w)
{
  const int t = blockIdx.x, tid = threadIdx.x;
  __shared__ float rs[4], rq[4];
  __shared__ float sp[4][E_];
  const float4 v = reinterpret_cast<const float4*>(x + (size_t)t*D_)[tid];
  float s  = v.x+v.y+v.z+v.w;
  float s2 = v.x*v.x+v.y*v.y+v.z*v.z+v.w*v.w;
  #pragma unroll
  for (int o=32;o;o>>=1){ s += __shfl_xor(s,o); s2 += __shfl_xor(s2,o); }
  const int wid=tid>>6, lane=tid&63;
  if (lane==0){ rs[wid]=s; rq[wid]=s2; }
  __syncthreads();
  s  = rs[0]+rs[1]+rs[2]+rs[3];
  s2 = rq[0]+rq[1]+rq[2]+rq[3];
  const float mu  = s*(1.0f/D_);
  const float var = s2*(1.0f/D_) - mu*mu;
  const float inv = rsqrtf(var + 1e-5f);
  const float4 gv = reinterpret_cast<const float4*>(g)[tid];
  const float4 bv = reinterpret_cast<const float4*>(bta)[tid];
  float oo[4];
  oo[0] = (v.x-mu)*inv*gv.x + bv.x;
  oo[1] = (v.y-mu)*inv*gv.y + bv.y;
  oo[2] = (v.z-mu)*inv*gv.z + bv.z;
  oo[3] = (v.w-mu)*inv*gv.w + bv.w;
  const size_t base = (size_t)t*D_ + tid*4;
  if (outf){ outf[base]=oo[0]; outf[base+1]=oo[1]; outf[base+2]=oo[2]; outf[base+3]=oo[3]; }
  if (OUTMODE==1){
    union { unsigned w[2]; u16x4 u; } hv;
    hv.w[0] = pk16(oo[0], oo[1]);
    hv.w[1] = pk16(oo[2], oo[3]);
    reinterpret_cast<u16x4*>(nout)[base>>2] = hv.u;
  } else {
    u16x4 hv;
    hv[0]=f2bf(oo[0]); hv[1]=f2bf(oo[1]); hv[2]=f2bf(oo[2]); hv[3]=f2bf(oo[3]);
    reinterpret_cast<u16x4*>(nout)[base>>2] = hv;
  }
  if (GATE){
    float part[E_];
    #pragma unroll
    for (int e=0;e<E_;e++){
      const float4 wv = reinterpret_cast<const float4*>(gw + (size_t)e*D_)[tid];
      part[e] = oo[0]*wv.x + oo[1]*wv.y + oo[2]*wv.z + oo[3]*wv.w;
    }
    #pragma unroll
    for (int e=0;e<E_;e++){
      #pragma unroll
      for (int o=32;o;o>>=1) part[e] += __shfl_xor(part[e], o);
    }
    if (lane==0){
      #pragma unroll
      for (int e=0;e<E_;e++) sp[wid][e] = part[e];
    }
    __syncthreads();
    if (tid==0){
      float lg[E_], mx=-3e38f;
      #pragma unroll
      for (int e=0;e<E_;e++){
        lg[e] = sp[0][e]+sp[1][e]+sp[2][e]+sp[3][e] + gb[e];
        mx = fmaxf(mx, lg[e]);
      }
      float ex[E_], sm=0.f;
      #pragma unroll
      for (int e=0;e<E_;e++){ ex[e]=__expf(lg[e]-mx); sm+=ex[e]; }
      float p[E_];
      #pragma unroll
      for (int e=0;e<E_;e++){ p[e]=ex[e]/sm; probs_out[(size_t)t*E_+e]=p[e]; }
      int i0=0; float l0=lg[0];
      #pragma unroll
      for (int e=1;e<E_;e++) if (lg[e]>l0){ l0=lg[e]; i0=e; }
      int i1=-1; float l1=-3e38f;
      #pragma unroll
      for (int e=0;e<E_;e++) if (e!=i0 && lg[e]>l1){ l1=lg[e]; i1=e; }
      top_i[2*t]=i0; top_i[2*t+1]=i1;
      const float v0=p[i0], v1=p[i1];
      const float swt=v0+v1;
      cw_w[2*t]=v0/swt; cw_w[2*t+1]=v1/swt;
    }
  }
}

// fp16 single-product QKV GEMM, LDS dbuf + counted vmcnt(4) pipeline,
// XCD-chunked 1D grid. NT = 24.
__global__ void __launch_bounds__(256) qkv_kernel(
    const _Float16* __restrict__ A, const _Float16* __restrict__ Bw,
    const float* __restrict__ bias,
    _Float16* __restrict__ qf, _Float16* __restrict__ kf, _Float16* __restrict__ vtf)
{
  __shared__ __align__(16) _Float16 Ash[2][128*32], Bsh[2][128*32];
  const int bid = blockIdx.x, nwg = gridDim.x;
  const int fid = (bid & 7)*(nwg>>3) + (bid>>3);
  const int nt = fid % 24, mt = fid / 24;
  const int tid=threadIdx.x, wid=tid>>6, lane=tid&63;
  const int wr=wid>>1, wc=wid&1;
  const int r16=lane&15, g4=lane>>4;
  const _Float16* Ag = A  + (size_t)mt*128*D_;
  const _Float16* Bg = Bw + (size_t)nt*128*D_;
  const int srow = wid*16 + (lane>>2);
  const int scol = (((lane&3) ^ ((lane>>3)&3)))*8;
  const int sl   = (g4 ^ ((r16>>1)&3))*8;
  f32x4 acc[4][4] = {};
#define QSTAGE(bi, k0) do { \
    _Pragma("unroll") \
    for (int p=0;p<2;p++){ \
      const int r  = p*64 + srow; \
      const int lo = (p*64 + wid*16)*32; \
      glds16(Ag + (size_t)r*D_ + (k0) + scol, &Ash[bi][lo]); \
      glds16(Bg + (size_t)r*D_ + (k0) + scol, &Bsh[bi][lo]); \
    } \
  } while(0)
  QSTAGE(0, 0);
  int cur = 0;
  for (int t=0; t<D_/32; ++t){
    if (t+1 < D_/32){
      QSTAGE(cur^1, (t+1)*32);
      asm volatile("s_waitcnt vmcnt(4)" ::: "memory");
    } else {
      asm volatile("s_waitcnt vmcnt(0)" ::: "memory");
    }
    __syncthreads();
    f16x8 af[4], bfr[4];
    #pragma unroll
    for (int m=0;m<4;m++) af[m]=ldH8(&Ash[cur][(wr*64+m*16+r16)*32 + sl]);
    #pragma unroll
    for (int n=0;n<4;n++) bfr[n]=ldH8(&Bsh[cur][(wc*64+n*16+r16)*32 + sl]);
    #pragma unroll
    for (int m=0;m<4;m++){
      #pragma unroll
      for (int n=0;n<4;n++) acc[m][n] = mfmaH(af[m], bfr[n], acc[m][n]);
    }
    __syncthreads();
    cur ^= 1;
  }
#undef QSTAGE
  #pragma unroll
  for (int m=0;m<4;m++){
    #pragma unroll
    for (int n=0;n<4;n++){
      #pragma unroll
      for (int r=0;r<4;r++){
        const int grow = mt*128 + wr*64 + m*16 + g4*4 + r;
        const int gcol = nt*128 + wc*64 + n*16 + r16;
        const float val = acc[m][n][r] + bias[gcol];
        const int which = gcol>>10, rem = gcol&1023;
        const int hh = rem>>6, ee = rem&63;
        const int bb = grow>>11, ss = grow&2047;
        if (which==0){
          qf[((size_t)(bb*H_+hh)*S_ + ss)*HD_ + ee] = (_Float16)(val * 0.18033688f);
        } else if (which==1){
          kf[((size_t)(bb*H_+hh)*S_ + ss)*HD_ + ee] = (_Float16)val;
        } else {
          const int p32 = 2*(ss & 12) + (ss & 3) + 4*((ss >> 4) & 1);
          const size_t idx = (((size_t)(bb*H_+hh)*(S_/32) + (ss>>5))*HD_ + ee)*32 + p32;
          vtf[idx] = (_Float16)val;
        }
      }
    }
  }
}

// out-proj GEMM: A = attn output (fp16 single), B = opw (fp16 hi/lo).
// 2-product fp32-equivalent. LDS dbuf (3 buffers) + vmcnt(6), XCD-chunked.
__global__ void __launch_bounds__(256) gemm3_kernel(
    const _Float16* __restrict__ A, int lda,
    const _Float16* __restrict__ Bh, const _Float16* __restrict__ Bl, int Kdim,
    const float* __restrict__ bias,
    const float* __restrict__ resid, float* __restrict__ x1out)
{
  __shared__ __align__(16) _Float16 Ash[2][128*32], Bsh[2][128*32], Bsl[2][128*32];
  const int bid = blockIdx.x, nwg = gridDim.x;
  const int fid = (bid & 7)*(nwg>>3) + (bid>>3);
  const int nt = fid & 7, mt = fid >> 3;
  const int tid=threadIdx.x, wid=tid>>6, lane=tid&63;
  const int wr=wid>>1, wc=wid&1;
  const int r16=lane&15, g4=lane>>4;
  const _Float16* Ag  = A  + (size_t)mt*128*lda;
  const _Float16* Bgh = Bh + (size_t)nt*128*Kdim;
  const _Float16* Bgl = Bl + (size_t)nt*128*Kdim;
  const int srow = wid*16 + (lane>>2);
  const int scol = (((lane&3) ^ ((lane>>3)&3)))*8;
  const int sl   = (g4 ^ ((r16>>1)&3))*8;
  f32x4 acc[4][4] = {};
#define G3STAGE(bi, k0) do { \
    _Pragma("unroll") \
    for (int p=0;p<2;p++){ \
      const int r  = p*64 + srow; \
      const int lo = (p*64 + wid*16)*32; \
      glds16(Ag  + (size_t)r*lda  + (k0) + scol, &Ash[bi][lo]); \
      glds16(Bgh + (size_t)r*Kdim + (k0) + scol, &Bsh[bi][lo]); \
      glds16(Bgl + (size_t)r*Kdim + (k0) + scol, &Bsl[bi][lo]); \
    } \
  } while(0)
  G3STAGE(0, 0);
  int cur = 0;
  const int NK = Kdim/32;
  for (int t=0; t<NK; ++t){
    if (t+1 < NK){
      G3STAGE(cur^1, (t+1)*32);
      asm volatile("s_waitcnt vmcnt(6)" ::: "memory");
    } else {
      asm volatile("s_waitcnt vmcnt(0)" ::: "memory");
    }
    __syncthreads();
    f16x8 af[4], bfh[4], bfl[4];
    #pragma unroll
    for (int m=0;m<4;m++){
      const int row = wr*64 + m*16 + r16;
      af[m] = ldH8(&Ash[cur][row*32 + sl]);
    }
    #pragma unroll
    for (int n=0;n<4;n++){
      const int row = wc*64 + n*16 + r16;
      bfh[n] = ldH8(&Bsh[cur][row*32 + sl]);
      bfl[n] = ldH8(&Bsl[cur][row*32 + sl]);
    }
    #pragma unroll
    for (int m=0;m<4;m++){
      #pragma unroll
      for (int n=0;n<4;n++){
        acc[m][n] = mfmaH(af[m], bfl[n], acc[m][n]);
        acc[m][n] = mfmaH(af[m], bfh[n], acc[m][n]);
      }
    }
    __syncthreads();
    cur ^= 1;
  }
#undef G3STAGE
  #pragma unroll
  for (int m=0;m<4;m++){
    #pragma unroll
    for (int n=0;n<4;n++){
      #pragma unroll
      for (int r=0;r<4;r++){
        const int grow = mt*128 + wr*64 + m*16 + g4*4 + r;
        const int gcol = nt*128 + wc*64 + n*16 + r16;
        const float val = acc[m][n][r] + bias[gcol];
        const size_t idx = (size_t)grow*D_ + gcol;
        x1out[idx] = val + resid[idx];
      }
    }
  }
}

// fused: fp16 flash attention v10 (blocks [0,ATTNB)) + FFN weight bf16
// conversion (blocks [ATTNB, ATTNB+CVTB), grid-stride). R20 measured-best.
__global__ void __launch_bounds__(512, 2) attn_cvt_kernel(
    const _Float16* __restrict__ Qf, const _Float16* __restrict__ Kf,
    const _Float16* __restrict__ Vtf, _Float16* __restrict__ Of,
    const float* __restrict__ w1, u16* __restrict__ w1b,
    const float* __restrict__ w2, u16* __restrict__ w2b, int n4each)
{
  const int bid = blockIdx.x;
  if (bid >= ATTNB){
    const int cb = bid - ATTNB;
    const size_t stride = (size_t)CVTB*512;
    for (size_t i = (size_t)cb*512 + threadIdx.x; i < (size_t)2*n4each; i += stride){
      const float* in; u16* out; size_t j;
      if (i < (size_t)n4each){ in = w1; out = w1b; j = i; }
      else                    { in = w2; out = w2b; j = i - n4each; }
      float4 v = reinterpret_cast<const float4*>(in)[j];
      u16x4 o;
      o[0]=f2bf(v.x); o[1]=f2bf(v.y); o[2]=f2bf(v.z); o[3]=f2bf(v.w);
      reinterpret_cast<u16x4*>(out)[j] = o;
    }
    return;
  }
  __shared__ __align__(16) _Float16 Kb[2][4096];
  __shared__ __align__(16) _Float16 Vb[2][4096];
  const int wg = (bid & 7) * 64 + (bid >> 3);   // 512 attn blocks
  const int bh = wg >> 4, qc = wg & 15;
  const int tid=threadIdx.x, wid=tid>>6, lane=tid&63;
  const int r16=lane&15, g4=lane>>4;
  const int q0 = qc*128 + wid*16;
  const _Float16* Qp = Qf  + (size_t)bh*S_*HD_ + (size_t)(q0+r16)*HD_ + g4*8;
  const _Float16* Kbase = Kf  + (size_t)bh*S_*HD_;
  const _Float16* Vbase = Vtf + (size_t)bh*HD_*S_;
  const f16x8 qf0 = ldH8(Qp);
  const f16x8 qf1 = ldH8(Qp+32);
  f32x4 of[4] = {};
  float m_run = -3e38f, lr = 0.f;

  const int kOff = (wid*8 + (lane>>3))*HD_ + (((lane&7) ^ ((lane>>3)&7)))*8;
  const int vOff = wid*512 + lane*8;
  const int sk0 = (g4 ^ (r16&7))*8;
  const int sk1 = ((g4+4) ^ (r16&7))*8;

#define STAGE(bi, tt) do { \
    glds16(Kbase + (size_t)(tt)*64*HD_ + kOff, (void*)&Kb[bi][wid*512]); \
    glds16(Vbase + (size_t)(tt)*4096   + vOff, (void*)&Vb[bi][wid*512]); \
  } while(0)

#define ATT_HALF(Kh_, Vh_) do { \
    const f16x8 k0v = ldH8((Kh_) + r16*64 + sk0); \
    const f16x8 k1v = ldH8((Kh_) + r16*64 + sk1); \
    const f16x8 k2v = ldH8((Kh_) + (16+r16)*64 + sk0); \
    const f16x8 k3v = ldH8((Kh_) + (16+r16)*64 + sk1); \
    f32x4 sA={}, sB={}; \
    __builtin_amdgcn_s_setprio(1); \
    sA = mfmaH(k0v, qf0, sA); sA = mfmaH(k1v, qf1, sA); \
    sB = mfmaH(k2v, qf0, sB); sB = mfmaH(k3v, qf1, sB); \
    __builtin_amdgcn_s_setprio(0); \
    const float t0=sA[0], t1=sA[1], t2=sA[2], t3=sA[3]; \
    const float t4=sB[0], t5=sB[1], t6=sB[2], t7=sB[3]; \
    const float lmx = fmaxf(fmaxf(fmaxf(t0,t1),fmaxf(t2,t3)), \
                            fmaxf(fmaxf(t4,t5),fmaxf(t6,t7))); \
    if (!__all(lmx <= m_run + 4.0f)) { \
      float mx = fmaxf(lmx, __shfl_xor(lmx,16)); \
      mx = fmaxf(mx, __shfl_xor(mx,32)); \
      const float mn = fmaxf(m_run, mx); \
      const float alp = __builtin_amdgcn_exp2f(m_run - mn); \
      m_run = mn; \
      lr *= alp; \
      const float ao0=__shfl(alp,4*g4), ao1=__shfl(alp,4*g4+1); \
      const float ao2=__shfl(alp,4*g4+2), ao3=__shfl(alp,4*g4+3); \
      _Pragma("unroll") \
      for (int c=0;c<4;c++){ of[c][0]*=ao0; of[c][1]*=ao1; of[c][2]*=ao2; of[c][3]*=ao3; } \
    } \
    const float msh = m_run - 9.0f; \
    const float p0=__builtin_amdgcn_exp2f(t0-msh), p1=__builtin_amdgcn_exp2f(t1-msh); \
    const float p2=__builtin_amdgcn_exp2f(t2-msh), p3=__builtin_amdgcn_exp2f(t3-msh); \
    const float p4=__builtin_amdgcn_exp2f(t4-msh), p5=__builtin_amdgcn_exp2f(t5-msh); \
    const float p6=__builtin_amdgcn_exp2f(t6-msh), p7=__builtin_amdgcn_exp2f(t7-msh); \
    lr += ((p0+p1)+(p2+p3)) + ((p4+p5)+(p6+p7)); \
    union { unsigned w[4]; f16x8 v; } pu; \
    pu.w[0]=pk16(p0,p1); pu.w[1]=pk16(p2,p3); \
    pu.w[2]=pk16(p4,p5); pu.w[3]=pk16(p6,p7); \
    const f16x8 v0v = ldH8((Vh_) + (r16)*32 + g4*8); \
    const f16x8 v1v = ldH8((Vh_) + (16+r16)*32 + g4*8); \
    const f16x8 v2v = ldH8((Vh_) + (32+r16)*32 + g4*8); \
    const f16x8 v3v = ldH8((Vh_) + (48+r16)*32 + g4*8); \
    __builtin_amdgcn_s_setprio(1); \
    of[0] = mfmaH(pu.v, v0v, of[0]); of[1] = mfmaH(pu.v, v1v, of[1]); \
    of[2] = mfmaH(pu.v, v2v, of[2]); of[3] = mfmaH(pu.v, v3v, of[3]); \
    __builtin_amdgcn_s_setprio(0); \
  } while(0)

  STAGE(0, 0);
  int cur = 0;

  for (int t=0; t<32; ++t){
    if (t < 31){
      STAGE(cur^1, t+1);
      asm volatile("s_waitcnt vmcnt(2)" ::: "memory");
    } else {
      asm volatile("s_waitcnt vmcnt(0)" ::: "memory");
    }
    __syncthreads();
    ATT_HALF(&Kb[cur][0],    &Vb[cur][0]);
    ATT_HALF(&Kb[cur][2048], &Vb[cur][2048]);
    __syncthreads();
    cur ^= 1;
  }
#undef ATT_HALF
#undef STAGE

  lr += __shfl_xor(lr,16);
  lr += __shfl_xor(lr,32);
  float li[4];
  #pragma unroll
  for (int r=0;r<4;r++) li[r] = 1.0f / __shfl(lr, 4*g4+r);
  const int bb = bh>>4, hh = bh&15;
  #pragma unroll
  for (int c=0;c<4;c++){
    #pragma unroll
    for (int r=0;r<4;r++){
      const float val = of[c][r] * li[r];
      const int qq = q0 + 4*g4 + r;
      const size_t idx = ((size_t)(bb*S_+qq))*D_ + hh*HD_ + c*16 + r16;
      Of[idx] = (_Float16)val;
    }
  }
}

// routing scan + fused load-balance loss (1 block, 512 threads).
__global__ void __launch_bounds__(512) scan_kernel(const int* __restrict__ top_i,
    int* __restrict__ goff, int* __restrict__ tile_expert,
    int* __restrict__ assign_token, int* __restrict__ pos_of,
    const float* __restrict__ probs, float* __restrict__ loss_out)
{
  __shared__ int cnt[E_];
  __shared__ int off[E_+1];
  __shared__ float sf[8][E_], sP[8][E_];
  const int tid=threadIdx.x;
  if (tid<E_) cnt[tid]=0;
  __syncthreads();
  for (int t=tid;t<T_;t+=512){
    atomicAdd(&cnt[top_i[2*t]],1);
    atomicAdd(&cnt[top_i[2*t+1]],1);
  }
  __syncthreads();
  if (tid==0){
    off[0]=0;
    for (int e=0;e<E_;e++) off[e+1]=off[e]+((cnt[e]+127)&~127);
    for (int i=0;i<=E_;i++) goff[i]=off[i];
  }
  __syncthreads();
  if (tid<MAXTILES){
    const int r=tid*128; int e=-1;
    for (int j=0;j<E_;j++) if (r>=off[j] && r<off[j+1]) e=j;
    tile_expert[tid]=e;
  }
  const int lane=tid&63;
  const int e=tid>>6;
  int base=off[e];
  for (int c=0;c<T_/64;c++){
    const int t=c*64+lane;
    const int a0=top_i[2*t], a1=top_i[2*t+1];
    const bool f=(a0==e)||(a1==e);
    const unsigned long long m=__ballot(f);
    if (f){
      const int pos = base + (int)__popcll(m & ((1ull<<lane)-1ull));
      assign_token[pos]=t;
      pos_of[2*t + (a0==e?0:1)] = pos;
    }
    base += (int)__popcll(m);
  }
  for (int r=base+lane; r<off[e+1]; r+=64) assign_token[r]=-1;
  __syncthreads();
  for (int r=off[E_]+tid; r<MAXROWS; r+=512) assign_token[r]=-1;
  // ---- fused load-balance loss ----
  float fc[E_]={0,0,0,0,0,0,0,0}, Ps[E_]={0,0,0,0,0,0,0,0};
  for (int t=tid;t<T_;t+=512){
    const float* pr = probs + (size_t)t*E_;
    const int a0 = top_i[2*t];
    #pragma unroll
    for (int k=0;k<E_;k++){
      Ps[k] += pr[k];
      fc[k] += (a0==k) ? 1.0f : 0.0f;
    }
  }
  #pragma unroll
  for (int k=0;k<E_;k++){
    #pragma unroll
    for (int o=32;o;o>>=1){ fc[k]+=__shfl_xor(fc[k],o); Ps[k]+=__shfl_xor(Ps[k],o); }
  }
  const int wid8 = tid>>6;
  if (lane==0){
    #pragma unroll
    for (int k=0;k<E_;k++){ sf[wid8][k]=fc[k]; sP[wid8][k]=Ps[k]; }
  }
  __syncthreads();
  if (tid==0){
    float loss=0.f;
    #pragma unroll
    for (int k=0;k<E_;k++){
      float fe=0.f, Pe=0.f;
      #pragma unroll
      for (int w=0;w<8;w++){ fe+=sf[w][k]; Pe+=sP[w][k]; }
      loss += (fe/(float)T_)*(Pe/(float)T_);
    }
    loss_out[0] = 0.01f*(float)E_*loss;
  }
}

// grouped bf16 GEMM, BK=32, LDS dbuf + counted vmcnt(4), XCD-chunked 1D grid.
// MODE 2: FFN1 + tanh-GELU, A gathered DIRECTLY from n2b via atok.
// MODE 3: FFN2, dense A. (R14/R18 measured-best configuration.)
template<int MODE>
__global__ void __launch_bounds__(256, 4) gemm_grp_kernel(
    const u16* __restrict__ A, int lda,
    const u16* __restrict__ Bbase, int Kdim, int Nsz, int NT,
    const float* __restrict__ bias,
    const int* __restrict__ tile_expert,
    const int* __restrict__ atok,
    u16* __restrict__ outp)
{
  const int bid = blockIdx.x, nwg = gridDim.x;
  const int fid = (bid & 7)*(nwg>>3) + (bid>>3);
  const int nt = fid % NT, mt = fid / NT;
  const int e = tile_expert[mt];
  if (e<0) return;
  __shared__ __align__(16) u16 Ash[2][128*32], Bsh[2][128*32];
  const int tid=threadIdx.x, wid=tid>>6, lane=tid&63;
  const int wr=wid>>1, wc=wid&1;
  const int r16=lane&15, g4=lane>>4;
  const float* bp = bias + (size_t)e*Nsz;
  const int srow = wid*16 + (lane>>2);
  const int scol = (((lane&3) ^ ((lane>>3)&3)))*8;
  const int sl   = (g4 ^ ((r16>>1)&3))*8;
  const u16* Bg = Bbase + (size_t)e*Nsz*Kdim + (size_t)nt*128*Kdim;
  size_t arow0, arow1;
  if (MODE==2){
    int t0 = atok[mt*128 + srow];      if (t0 < 0) t0 = 0;
    int t1 = atok[mt*128 + 64 + srow]; if (t1 < 0) t1 = 0;
    arow0 = (size_t)t0*lda;
    arow1 = (size_t)t1*lda;
  } else {
    arow0 = (size_t)(mt*128 + srow)*lda;
    arow1 = (size_t)(mt*128 + 64 + srow)*lda;
  }
  f32x4 acc[4][4] = {};
#define GSTAGE(bi, k0) do { \
    glds16(A + arow0 + (k0) + scol, &Ash[bi][(wid*16)*32]); \
    glds16(A + arow1 + (k0) + scol, &Ash[bi][(64 + wid*16)*32]); \
    glds16(Bg + (size_t)(srow)*Kdim      + (k0) + scol, &Bsh[bi][(wid*16)*32]); \
    glds16(Bg + (size_t)(64+srow)*Kdim   + (k0) + scol, &Bsh[bi][(64 + wid*16)*32]); \
  } while(0)
  GSTAGE(0, 0);
  int cur = 0;
  const int NK = Kdim/32;
  for (int t=0; t<NK; ++t){
    if (t+1 < NK){
      GSTAGE(cur^1, (t+1)*32);
      asm volatile("s_waitcnt vmcnt(4)" ::: "memory");
    } else {
      asm volatile("s_waitcnt vmcnt(0)" ::: "memory");
    }
    __syncthreads();
    bf16x8 af[4], bfr[4];
    #pragma unroll
    for (int m=0;m<4;m++) af[m]=ld8(&Ash[cur][(wr*64+m*16+r16)*32 + sl]);
    #pragma unroll
    for (int n=0;n<4;n++) bfr[n]=ld8(&Bsh[cur][(wc*64+n*16+r16)*32 + sl]);
    #pragma unroll
    for (int m=0;m<4;m++){
      #pragma unroll
      for (int n=0;n<4;n++) acc[m][n] = mfma16(af[m], bfr[n], acc[m][n]);
    }
    __syncthreads();
    cur ^= 1;
  }
#undef GSTAGE
  #pragma unroll
  for (int m=0;m<4;m++){
    #pragma unroll
    for (int n=0;n<4;n++){
      #pragma unroll
      for (int r=0;r<4;r++){
        const int grow = mt*128 + wr*64 + m*16 + g4*4 + r;
        const int gcol = nt*128 + wc*64 + n*16 + r16;
        float val = acc[m][n][r] + bp[gcol];
        if (MODE==2){
          const float z = val*(1.0f + 0.044715f*val*val)*2.3021622f;
          val = val / (1.0f + __builtin_amdgcn_exp2f(-z));
        }
        outp[(size_t)grow*Nsz + gcol] = f2bf(val);
      }
    }
  }
}

__global__ void __launch_bounds__(256) combine_kernel(const float* __restrict__ x1,
    const u16* __restrict__ eo, const int* __restrict__ pos_of, const float* __restrict__ cw_w,
    float* __restrict__ out0)
{
  const int t=blockIdx.x, tid=threadIdx.x;
  const int r0=pos_of[2*t], r1=pos_of[2*t+1];
  const float w0=cw_w[2*t], w1=cw_w[2*t+1];
  const u16x4 e0 = reinterpret_cast<const u16x4*>(eo + (size_t)r0*D_)[tid];
  const u16x4 e1 = reinterpret_cast<const u16x4*>(eo + (size_t)r1*D_)[tid];
  const float4 xv = reinterpret_cast<const float4*>(x1 + (size_t)t*D_)[tid];
  float4 o;
  o.x = xv.x + w0*bf2f(e0[0]) + w1*bf2f(e1[0]);
  o.y = xv.y + w0*bf2f(e0[1]) + w1*bf2f(e1[1]);
  o.z = xv.z + w0*bf2f(e0[2]) + w1*bf2f(e1[2]);
  o.w = xv.w + w0*bf2f(e0[3]) + w1*bf2f(e1[3]);
  reinterpret_cast<float4*>(out0 + (size_t)t*D_)[tid] = o;
}

static inline size_t alup(size_t x){ return (x+255)&~(size_t)255; }

extern "C" void kernel_launch(void* const* d_in, const int* in_sizes, int n_in,
                              void* d_out, int out_size, void* d_ws, size_t ws_size,
                              hipStream_t stream) {
  (void)in_sizes; (void)n_in; (void)out_size; (void)ws_size;
  const float* x    = (const float*)d_in[0];
  const float* ipw  = (const float*)d_in[1];
  const float* ipb  = (const float*)d_in[2];
  const float* opw  = (const float*)d_in[3];
  const float* opb  = (const float*)d_in[4];
  const float* ln1g = (const float*)d_in[5];
  const float* ln1b = (const float*)d_in[6];
  const float* ln2g = (const float*)d_in[7];
  const float* ln2b = (const float*)d_in[8];
  const float* gw   = (const float*)d_in[9];
  const float* gb   = (const float*)d_in[10];
  const float* w1   = (const float*)d_in[11];
  const float* b1   = (const float*)d_in[12];
  const float* w2   = (const float*)d_in[13];
  const float* b2   = (const float*)d_in[14];

  float* out0       = (float*)d_out;
  float* loss_out   = out0 + (size_t)T_*D_;
  float* probs_out  = loss_out + 1;
  float* normed_out = probs_out + (size_t)T_*E_;

  char* p = (char*)d_ws;
  auto take = [&](size_t bytes)->void*{ void* r = (void*)p; p += alup(bytes); return r; };

  _Float16* wipf  = (_Float16*)take((size_t)3*D_*D_*2);
  _Float16* wophf = (_Float16*)take((size_t)D_*D_*2);
  _Float16* woplf = (_Float16*)take((size_t)D_*D_*2);
  u16* w1b   = (u16*)take((size_t)E_*FF_*D_*2);
  u16* w2b   = (u16*)take((size_t)E_*D_*FF_*2);
  _Float16* nf16 = (_Float16*)take((size_t)T_*D_*2);
  _Float16* qf  = (_Float16*)take((size_t)T_*D_*2);
  _Float16* kf  = (_Float16*)take((size_t)T_*D_*2);
  _Float16* vtf = (_Float16*)take((size_t)T_*D_*2);
  _Float16* of16 = (_Float16*)take((size_t)T_*D_*2);
  float* x1  = (float*)take((size_t)T_*D_*4);
  u16* n2b   = (u16*)take((size_t)T_*D_*2);
  u16* hbuf  = (u16*)take((size_t)MAXROWS*FF_*2);
  u16* eo    = (u16*)take((size_t)MAXROWS*D_*2);
  int* top_i = (int*)take((size_t)T_*2*4);
  float* cww = (float*)take((size_t)T_*2*4);
  int* posof = (int*)take((size_t)T_*2*4);
  int* goff  = (int*)take((size_t)(E_+1)*4);
  int* texp  = (int*)take((size_t)MAXTILES*4);
  int* atok  = (int*)take((size_t)MAXROWS*4);

  cvt_wproj_kernel<<<(3*D_*D_/4 + D_*D_/4 + 255)/256, 256, 0, stream>>>(
      ipw, wipf, opw, wophf, woplf, 3*D_*D_/4, D_*D_/4);

  ln_kernel<1,0><<<T_, 256, 0, stream>>>(x, ln1g, ln1b, normed_out, (u16*)nf16,
                                         nullptr, nullptr, nullptr, nullptr, nullptr);

  qkv_kernel<<<dim3(24*(T_/128)), 256, 0, stream>>>(nf16, wipf, ipb, qf, kf, vtf);

  attn_cvt_kernel<<<ATTNB + CVTB, 512, 0, stream>>>(qf, kf, vtf, of16,
                                                    w1, w1b, w2, w2b, E_*FF_*D_/4);

  gemm3_kernel<<<dim3(8*(T_/128)), 256, 0, stream>>>(
      of16, D_, wophf, woplf, D_, opb, x, x1);

  ln_kernel<2,1><<<T_, 256, 0, stream>>>(x1, ln2g, ln2b, nullptr, n2b,
                                         gw, gb, probs_out, top_i, cww);

  scan_kernel<<<1, 512, 0, stream>>>(top_i, goff, texp, atok, posof, probs_out, loss_out);

  gemm_grp_kernel<2><<<dim3((FF_/128)*MAXTILES), 256, 0, stream>>>(n2b, D_, w1b, D_, FF_, FF_/128, b1, texp, atok, hbuf);
  gemm_grp_kernel<3><<<dim3((D_/128)*MAXTILES), 256, 0, stream>>>(hbuf, FF_, w2b, FF_, D_, D_/128, b2, texp, nullptr, eo);

  combine_kernel<<<T_, 256, 0, stream>>>(x1, eo, posof, cww, out0);
}

// Round 26
// 493.557 us; speedup vs baseline: 1.0371x; 1.0012x over previous
//
#include <hip/hip_runtime.h>
#include <math.h>

#define D_ 1024
#define H_ 16
#define HD_ 64
#define FF_ 4096
#define E_ 8
#define B_ 2
#define S_ 2048
#define T_ 4096
#define MAXROWS 9216
#define MAXTILES 72
#define ATTNB 512
#define CVTB 512

typedef unsigned short u16;
typedef __attribute__((ext_vector_type(4))) float f32x4;
typedef __attribute__((ext_vector_type(8))) __bf16 bf16x8;
typedef __attribute__((ext_vector_type(8))) _Float16 f16x8;
typedef __attribute__((ext_vector_type(4))) unsigned short u16x4;

__device__ __forceinline__ u16 f2bf(float f){
  union { float f; unsigned u; } v; v.f = f;
  unsigned r = v.u + 0x7fffu + ((v.u >> 16) & 1u);
  return (u16)(r >> 16);
}
__device__ __forceinline__ float bf2f(u16 h){
  union { unsigned u; float f; } v; v.u = ((unsigned)h) << 16;
  return v.f;
}
__device__ __forceinline__ void glds16(const void* g, void* l){
  __builtin_amdgcn_global_load_lds((const __attribute__((address_space(1))) void*)g,
                                   (__attribute__((address_space(3))) void*)l, 16, 0, 0);
}
__device__ __forceinline__ bf16x8 ld8(const u16* p){
  return *reinterpret_cast<const bf16x8*>(p);
}
__device__ __forceinline__ f16x8 ldH8(const _Float16* p){
  return *reinterpret_cast<const f16x8*>(p);
}
__device__ __forceinline__ f32x4 mfma16(bf16x8 a, bf16x8 b, f32x4 c){
  return __builtin_amdgcn_mfma_f32_16x16x32_bf16(a, b, c, 0, 0, 0);
}
__device__ __forceinline__ f32x4 mfmaH(f16x8 a, f16x8 b, f32x4 c){
  return __builtin_amdgcn_mfma_f32_16x16x32_f16(a, b, c, 0, 0, 0);
}
__device__ __forceinline__ unsigned pk16(float a, float b){
  auto pk = __builtin_amdgcn_cvt_pkrtz(a, b);
  return __builtin_bit_cast(unsigned, pk);
}

// OUTMODE 1: fp16 out; OUTMODE 2: bf16 out. GATE: fused MoE gate.
// When ipw != nullptr, blocks [T_, T_+4096) perform the projection-weight
// conversion (ipw -> fp16, opw -> fp16 hi/lo) — fused to absorb the
// standalone cvt_wproj launch under ln1's wall time.
template<int OUTMODE, int GATE>
__global__ void __launch_bounds__(256) ln_kernel(const float* __restrict__ x, const float* __restrict__ g,
    const float* __restrict__ bta, float* __restrict__ outf, u16* __restrict__ nout,
    const float* __restrict__ gw, const float* __restrict__ gb,
    float* __restrict__ probs_out, int* __restrict__ top_i, float* __restrict__ cw_w,
    const float* __restrict__ ipw, _Float16* __restrict__ wipf,
    const float* __restrict__ opw, _Float16* __restrict__ woph, _Float16* __restrict__ wopl,
    int n4a, int n4b)
{
  const int t = blockIdx.x, tid = threadIdx.x;
  if (ipw && t >= T_){
    const int i = (t - T_)*256 + tid;
    if (i < n4a){
      float4 v = reinterpret_cast<const float4*>(ipw)[i];
      union { unsigned w[2]; u16x4 u; } o;
      o.w[0] = pk16(v.x, v.y);
      o.w[1] = pk16(v.z, v.w);
      reinterpret_cast<u16x4*>(wipf)[i] = o.u;
    } else if (i < n4a + n4b){
      const int j = i - n4a;
      float4 v = reinterpret_cast<const float4*>(opw)[j];
      float vv[4] = {v.x, v.y, v.z, v.w};
      u16x4 h, l;
      #pragma unroll
      for (int k=0;k<4;k++){
        const _Float16 hh = (_Float16)vv[k];
        const _Float16 ll = (_Float16)(vv[k] - (float)hh);
        h[k] = __builtin_bit_cast(u16, hh);
        l[k] = __builtin_bit_cast(u16, ll);
      }
      reinterpret_cast<u16x4*>(woph)[j] = h;
      reinterpret_cast<u16x4*>(wopl)[j] = l;
    }
    return;
  }
  __shared__ float rs[4], rq[4];
  __shared__ float sp[4][E_];
  const float4 v = reinterpret_cast<const float4*>(x + (size_t)t*D_)[tid];
  float s  = v.x+v.y+v.z+v.w;
  float s2 = v.x*v.x+v.y*v.y+v.z*v.z+v.w*v.w;
  #pragma unroll
  for (int o=32;o;o>>=1){ s += __shfl_xor(s,o); s2 += __shfl_xor(s2,o); }
  const int wid=tid>>6, lane=tid&63;
  if (lane==0){ rs[wid]=s; rq[wid]=s2; }
  __syncthreads();
  s  = rs[0]+rs[1]+rs[2]+rs[3];
  s2 = rq[0]+rq[1]+rq[2]+rq[3];
  const float mu  = s*(1.0f/D_);
  const float var = s2*(1.0f/D_) - mu*mu;
  const float inv = rsqrtf(var + 1e-5f);
  const float4 gv = reinterpret_cast<const float4*>(g)[tid];
  const float4 bv = reinterpret_cast<const float4*>(bta)[tid];
  float oo[4];
  oo[0] = (v.x-mu)*inv*gv.x + bv.x;
  oo[1] = (v.y-mu)*inv*gv.y + bv.y;
  oo[2] = (v.z-mu)*inv*gv.z + bv.z;
  oo[3] = (v.w-mu)*inv*gv.w + bv.w;
  const size_t base = (size_t)t*D_ + tid*4;
  if (outf){ outf[base]=oo[0]; outf[base+1]=oo[1]; outf[base+2]=oo[2]; outf[base+3]=oo[3]; }
  if (OUTMODE==1){
    union { unsigned w[2]; u16x4 u; } hv;
    hv.w[0] = pk16(oo[0], oo[1]);
    hv.w[1] = pk16(oo[2], oo[3]);
    reinterpret_cast<u16x4*>(nout)[base>>2] = hv.u;
  } else {
    u16x4 hv;
    hv[0]=f2bf(oo[0]); hv[1]=f2bf(oo[1]); hv[2]=f2bf(oo[2]); hv[3]=f2bf(oo[3]);
    reinterpret_cast<u16x4*>(nout)[base>>2] = hv;
  }
  if (GATE){
    float part[E_];
    #pragma unroll
    for (int e=0;e<E_;e++){
      const float4 wv = reinterpret_cast<const float4*>(gw + (size_t)e*D_)[tid];
      part[e] = oo[0]*wv.x + oo[1]*wv.y + oo[2]*wv.z + oo[3]*wv.w;
    }
    #pragma unroll
    for (int e=0;e<E_;e++){
      #pragma unroll
      for (int o=32;o;o>>=1) part[e] += __shfl_xor(part[e], o);
    }
    if (lane==0){
      #pragma unroll
      for (int e=0;e<E_;e++) sp[wid][e] = part[e];
    }
    __syncthreads();
    if (tid==0){
      float lg[E_], mx=-3e38f;
      #pragma unroll
      for (int e=0;e<E_;e++){
        lg[e] = sp[0][e]+sp[1][e]+sp[2][e]+sp[3][e] + gb[e];
        mx = fmaxf(mx, lg[e]);
      }
      float ex[E_], sm=0.f;
      #pragma unroll
      for (int e=0;e<E_;e++){ ex[e]=__expf(lg[e]-mx); sm+=ex[e]; }
      float p[E_];
      #pragma unroll
      for (int e=0;e<E_;e++){ p[e]=ex[e]/sm; probs_out[(size_t)t*E_+e]=p[e]; }
      int i0=0; float l0=lg[0];
      #pragma unroll
      for (int e=1;e<E_;e++) if (lg[e]>l0){ l0=lg[e]; i0=e; }
      int i1=-1; float l1=-3e38f;
      #pragma unroll
      for (int e=0;e<E_;e++) if (e!=i0 && lg[e]>l1){ l1=lg[e]; i1=e; }
      top_i[2*t]=i0; top_i[2*t+1]=i1;
      const float v0=p[i0], v1=p[i1];
      const float swt=v0+v1;
      cw_w[2*t]=v0/swt; cw_w[2*t+1]=v1/swt;
    }
  }
}

// fp16 single-product QKV GEMM, LDS dbuf + counted vmcnt(4) pipeline,
// XCD-chunked 1D grid. NT = 24.
__global__ void __launch_bounds__(256) qkv_kernel(
    const _Float16* __restrict__ A, const _Float16* __restrict__ Bw,
    const float* __restrict__ bias,
    _Float16* __restrict__ qf, _Float16* __restrict__ kf, _Float16* __restrict__ vtf)
{
  __shared__ __align__(16) _Float16 Ash[2][128*32], Bsh[2][128*32];
  const int bid = blockIdx.x, nwg = gridDim.x;
  const int fid = (bid & 7)*(nwg>>3) + (bid>>3);
  const int nt = fid % 24, mt = fid / 24;
  const int tid=threadIdx.x, wid=tid>>6, lane=tid&63;
  const int wr=wid>>1, wc=wid&1;
  const int r16=lane&15, g4=lane>>4;
  const _Float16* Ag = A  + (size_t)mt*128*D_;
  const _Float16* Bg = Bw + (size_t)nt*128*D_;
  const int srow = wid*16 + (lane>>2);
  const int scol = (((lane&3) ^ ((lane>>3)&3)))*8;
  const int sl   = (g4 ^ ((r16>>1)&3))*8;
  f32x4 acc[4][4] = {};
#define QSTAGE(bi, k0) do { \
    _Pragma("unroll") \
    for (int p=0;p<2;p++){ \
      const int r  = p*64 + srow; \
      const int lo = (p*64 + wid*16)*32; \
      glds16(Ag + (size_t)r*D_ + (k0) + scol, &Ash[bi][lo]); \
      glds16(Bg + (size_t)r*D_ + (k0) + scol, &Bsh[bi][lo]); \
    } \
  } while(0)
  QSTAGE(0, 0);
  int cur = 0;
  for (int t=0; t<D_/32; ++t){
    if (t+1 < D_/32){
      QSTAGE(cur^1, (t+1)*32);
      asm volatile("s_waitcnt vmcnt(4)" ::: "memory");
    } else {
      asm volatile("s_waitcnt vmcnt(0)" ::: "memory");
    }
    __syncthreads();
    f16x8 af[4], bfr[4];
    #pragma unroll
    for (int m=0;m<4;m++) af[m]=ldH8(&Ash[cur][(wr*64+m*16+r16)*32 + sl]);
    #pragma unroll
    for (int n=0;n<4;n++) bfr[n]=ldH8(&Bsh[cur][(wc*64+n*16+r16)*32 + sl]);
    #pragma unroll
    for (int m=0;m<4;m++){
      #pragma unroll
      for (int n=0;n<4;n++) acc[m][n] = mfmaH(af[m], bfr[n], acc[m][n]);
    }
    __syncthreads();
    cur ^= 1;
  }
#undef QSTAGE
  #pragma unroll
  for (int m=0;m<4;m++){
    #pragma unroll
    for (int n=0;n<4;n++){
      #pragma unroll
      for (int r=0;r<4;r++){
        const int grow = mt*128 + wr*64 + m*16 + g4*4 + r;
        const int gcol = nt*128 + wc*64 + n*16 + r16;
        const float val = acc[m][n][r] + bias[gcol];
        const int which = gcol>>10, rem = gcol&1023;
        const int hh = rem>>6, ee = rem&63;
        const int bb = grow>>11, ss = grow&2047;
        if (which==0){
          qf[((size_t)(bb*H_+hh)*S_ + ss)*HD_ + ee] = (_Float16)(val * 0.18033688f);
        } else if (which==1){
          kf[((size_t)(bb*H_+hh)*S_ + ss)*HD_ + ee] = (_Float16)val;
        } else {
          const int p32 = 2*(ss & 12) + (ss & 3) + 4*((ss >> 4) & 1);
          const size_t idx = (((size_t)(bb*H_+hh)*(S_/32) + (ss>>5))*HD_ + ee)*32 + p32;
          vtf[idx] = (_Float16)val;
        }
      }
    }
  }
}

// out-proj GEMM: A = attn output (fp16 single), B = opw (fp16 hi/lo).
// 2-product fp32-equivalent. LDS dbuf (3 buffers) + vmcnt(6), XCD-chunked.
__global__ void __launch_bounds__(256) gemm3_kernel(
    const _Float16* __restrict__ A, int lda,
    const _Float16* __restrict__ Bh, const _Float16* __restrict__ Bl, int Kdim,
    const float* __restrict__ bias,
    const float* __restrict__ resid, float* __restrict__ x1out)
{
  __shared__ __align__(16) _Float16 Ash[2][128*32], Bsh[2][128*32], Bsl[2][128*32];
  const int bid = blockIdx.x, nwg = gridDim.x;
  const int fid = (bid & 7)*(nwg>>3) + (bid>>3);
  const int nt = fid & 7, mt = fid >> 3;
  const int tid=threadIdx.x, wid=tid>>6, lane=tid&63;
  const int wr=wid>>1, wc=wid&1;
  const int r16=lane&15, g4=lane>>4;
  const _Float16* Ag  = A  + (size_t)mt*128*lda;
  const _Float16* Bgh = Bh + (size_t)nt*128*Kdim;
  const _Float16* Bgl = Bl + (size_t)nt*128*Kdim;
  const int srow = wid*16 + (lane>>2);
  const int scol = (((lane&3) ^ ((lane>>3)&3)))*8;
  const int sl   = (g4 ^ ((r16>>1)&3))*8;
  f32x4 acc[4][4] = {};
#define G3STAGE(bi, k0) do { \
    _Pragma("unroll") \
    for (int p=0;p<2;p++){ \
      const int r  = p*64 + srow; \
      const int lo = (p*64 + wid*16)*32; \
      glds16(Ag  + (size_t)r*lda  + (k0) + scol, &Ash[bi][lo]); \
      glds16(Bgh + (size_t)r*Kdim + (k0) + scol, &Bsh[bi][lo]); \
      glds16(Bgl + (size_t)r*Kdim + (k0) + scol, &Bsl[bi][lo]); \
    } \
  } while(0)
  G3STAGE(0, 0);
  int cur = 0;
  const int NK = Kdim/32;
  for (int t=0; t<NK; ++t){
    if (t+1 < NK){
      G3STAGE(cur^1, (t+1)*32);
      asm volatile("s_waitcnt vmcnt(6)" ::: "memory");
    } else {
      asm volatile("s_waitcnt vmcnt(0)" ::: "memory");
    }
    __syncthreads();
    f16x8 af[4], bfh[4], bfl[4];
    #pragma unroll
    for (int m=0;m<4;m++){
      const int row = wr*64 + m*16 + r16;
      af[m] = ldH8(&Ash[cur][row*32 + sl]);
    }
    #pragma unroll
    for (int n=0;n<4;n++){
      const int row = wc*64 + n*16 + r16;
      bfh[n] = ldH8(&Bsh[cur][row*32 + sl]);
      bfl[n] = ldH8(&Bsl[cur][row*32 + sl]);
    }
    #pragma unroll
    for (int m=0;m<4;m++){
      #pragma unroll
      for (int n=0;n<4;n++){
        acc[m][n] = mfmaH(af[m], bfl[n], acc[m][n]);
        acc[m][n] = mfmaH(af[m], bfh[n], acc[m][n]);
      }
    }
    __syncthreads();
    cur ^= 1;
  }
#undef G3STAGE
  #pragma unroll
  for (int m=0;m<4;m++){
    #pragma unroll
    for (int n=0;n<4;n++){
      #pragma unroll
      for (int r=0;r<4;r++){
        const int grow = mt*128 + wr*64 + m*16 + g4*4 + r;
        const int gcol = nt*128 + wc*64 + n*16 + r16;
        const float val = acc[m][n][r] + bias[gcol];
        const size_t idx = (size_t)grow*D_ + gcol;
        x1out[idx] = val + resid[idx];
      }
    }
  }
}

// fused: fp16 flash attention v10 (blocks [0,ATTNB)) + FFN weight bf16
// conversion (blocks [ATTNB, ATTNB+CVTB), grid-stride). R20 measured-best.
__global__ void __launch_bounds__(512, 2) attn_cvt_kernel(
    const _Float16* __restrict__ Qf, const _Float16* __restrict__ Kf,
    const _Float16* __restrict__ Vtf, _Float16* __restrict__ Of,
    const float* __restrict__ w1, u16* __restrict__ w1b,
    const float* __restrict__ w2, u16* __restrict__ w2b, int n4each)
{
  const int bid = blockIdx.x;
  if (bid >= ATTNB){
    const int cb = bid - ATTNB;
    const size_t stride = (size_t)CVTB*512;
    for (size_t i = (size_t)cb*512 + threadIdx.x; i < (size_t)2*n4each; i += stride){
      const float* in; u16* out; size_t j;
      if (i < (size_t)n4each){ in = w1; out = w1b; j = i; }
      else                    { in = w2; out = w2b; j = i - n4each; }
      float4 v = reinterpret_cast<const float4*>(in)[j];
      u16x4 o;
      o[0]=f2bf(v.x); o[1]=f2bf(v.y); o[2]=f2bf(v.z); o[3]=f2bf(v.w);
      reinterpret_cast<u16x4*>(out)[j] = o;
    }
    return;
  }
  __shared__ __align__(16) _Float16 Kb[2][4096];
  __shared__ __align__(16) _Float16 Vb[2][4096];
  const int wg = (bid & 7) * 64 + (bid >> 3);   // 512 attn blocks
  const int bh = wg >> 4, qc = wg & 15;
  const int tid=threadIdx.x, wid=tid>>6, lane=tid&63;
  const int r16=lane&15, g4=lane>>4;
  const int q0 = qc*128 + wid*16;
  const _Float16* Qp = Qf  + (size_t)bh*S_*HD_ + (size_t)(q0+r16)*HD_ + g4*8;
  const _Float16* Kbase = Kf  + (size_t)bh*S_*HD_;
  const _Float16* Vbase = Vtf + (size_t)bh*HD_*S_;
  const f16x8 qf0 = ldH8(Qp);
  const f16x8 qf1 = ldH8(Qp+32);
  f32x4 of[4] = {};
  float m_run = -3e38f, lr = 0.f;

  const int kOff = (wid*8 + (lane>>3))*HD_ + (((lane&7) ^ ((lane>>3)&7)))*8;
  const int vOff = wid*512 + lane*8;
  const int sk0 = (g4 ^ (r16&7))*8;
  const int sk1 = ((g4+4) ^ (r16&7))*8;

#define STAGE(bi, tt) do { \
    glds16(Kbase + (size_t)(tt)*64*HD_ + kOff, (void*)&Kb[bi][wid*512]); \
    glds16(Vbase + (size_t)(tt)*4096   + vOff, (void*)&Vb[bi][wid*512]); \
  } while(0)

#define ATT_HALF(Kh_, Vh_) do { \
    const f16x8 k0v = ldH8((Kh_) + r16*64 + sk0); \
    const f16x8 k1v = ldH8((Kh_) + r16*64 + sk1); \
    const f16x8 k2v = ldH8((Kh_) + (16+r16)*64 + sk0); \
    const f16x8 k3v = ldH8((Kh_) + (16+r16)*64 + sk1); \
    f32x4 sA={}, sB={}; \
    __builtin_amdgcn_s_setprio(1); \
    sA = mfmaH(k0v, qf0, sA); sA = mfmaH(k1v, qf1, sA); \
    sB = mfmaH(k2v, qf0, sB); sB = mfmaH(k3v, qf1, sB); \
    __builtin_amdgcn_s_setprio(0); \
    const float t0=sA[0], t1=sA[1], t2=sA[2], t3=sA[3]; \
    const float t4=sB[0], t5=sB[1], t6=sB[2], t7=sB[3]; \
    const float lmx = fmaxf(fmaxf(fmaxf(t0,t1),fmaxf(t2,t3)), \
                            fmaxf(fmaxf(t4,t5),fmaxf(t6,t7))); \
    if (!__all(lmx <= m_run + 4.0f)) { \
      float mx = fmaxf(lmx, __shfl_xor(lmx,16)); \
      mx = fmaxf(mx, __shfl_xor(mx,32)); \
      const float mn = fmaxf(m_run, mx); \
      const float alp = __builtin_amdgcn_exp2f(m_run - mn); \
      m_run = mn; \
      lr *= alp; \
      const float ao0=__shfl(alp,4*g4), ao1=__shfl(alp,4*g4+1); \
      const float ao2=__shfl(alp,4*g4+2), ao3=__shfl(alp,4*g4+3); \
      _Pragma("unroll") \
      for (int c=0;c<4;c++){ of[c][0]*=ao0; of[c][1]*=ao1; of[c][2]*=ao2; of[c][3]*=ao3; } \
    } \
    const float msh = m_run - 9.0f; \
    const float p0=__builtin_amdgcn_exp2f(t0-msh), p1=__builtin_amdgcn_exp2f(t1-msh); \
    const float p2=__builtin_amdgcn_exp2f(t2-msh), p3=__builtin_amdgcn_exp2f(t3-msh); \
    const float p4=__builtin_amdgcn_exp2f(t4-msh), p5=__builtin_amdgcn_exp2f(t5-msh); \
    const float p6=__builtin_amdgcn_exp2f(t6-msh), p7=__builtin_amdgcn_exp2f(t7-msh); \
    lr += ((p0+p1)+(p2+p3)) + ((p4+p5)+(p6+p7)); \
    union { unsigned w[4]; f16x8 v; } pu; \
    pu.w[0]=pk16(p0,p1); pu.w[1]=pk16(p2,p3); \
    pu.w[2]=pk16(p4,p5); pu.w[3]=pk16(p6,p7); \
    const f16x8 v0v = ldH8((Vh_) + (r16)*32 + g4*8); \
    const f16x8 v1v = ldH8((Vh_) + (16+r16)*32 + g4*8); \
    const f16x8 v2v = ldH8((Vh_) + (32+r16)*32 + g4*8); \
    const f16x8 v3v = ldH8((Vh_) + (48+r16)*32 + g4*8); \
    __builtin_amdgcn_s_setprio(1); \
    of[0] = mfmaH(pu.v, v0v, of[0]); of[1] = mfmaH(pu.v, v1v, of[1]); \
    of[2] = mfmaH(pu.v, v2v, of[2]); of[3] = mfmaH(pu.v, v3v, of[3]); \
    __builtin_amdgcn_s_setprio(0); \
  } while(0)

  STAGE(0, 0);
  int cur = 0;

  for (int t=0; t<32; ++t){
    if (t < 31){
      STAGE(cur^1, t+1);
      asm volatile("s_waitcnt vmcnt(2)" ::: "memory");
    } else {
      asm volatile("s_waitcnt vmcnt(0)" ::: "memory");
    }
    __syncthreads();
    ATT_HALF(&Kb[cur][0],    &Vb[cur][0]);
    ATT_HALF(&Kb[cur][2048], &Vb[cur][2048]);
    __syncthreads();
    cur ^= 1;
  }
#undef ATT_HALF
#undef STAGE

  lr += __shfl_xor(lr,16);
  lr += __shfl_xor(lr,32);
  float li[4];
  #pragma unroll
  for (int r=0;r<4;r++) li[r] = 1.0f / __shfl(lr, 4*g4+r);
  const int bb = bh>>4, hh = bh&15;
  #pragma unroll
  for (int c=0;c<4;c++){
    #pragma unroll
    for (int r=0;r<4;r++){
      const float val = of[c][r] * li[r];
      const int qq = q0 + 4*g4 + r;
      const size_t idx = ((size_t)(bb*S_+qq))*D_ + hh*HD_ + c*16 + r16;
      Of[idx] = (_Float16)val;
    }
  }
}

// routing scan + fused load-balance loss (1 block, 512 threads).
__global__ void __launch_bounds__(512) scan_kernel(const int* __restrict__ top_i,
    int* __restrict__ goff, int* __restrict__ tile_expert,
    int* __restrict__ assign_token, int* __restrict__ pos_of,
    const float* __restrict__ probs, float* __restrict__ loss_out)
{
  __shared__ int cnt[E_];
  __shared__ int off[E_+1];
  __shared__ float sf[8][E_], sP[8][E_];
  const int tid=threadIdx.x;
  if (tid<E_) cnt[tid]=0;
  __syncthreads();
  for (int t=tid;t<T_;t+=512){
    atomicAdd(&cnt[top_i[2*t]],1);
    atomicAdd(&cnt[top_i[2*t+1]],1);
  }
  __syncthreads();
  if (tid==0){
    off[0]=0;
    for (int e=0;e<E_;e++) off[e+1]=off[e]+((cnt[e]+127)&~127);
    for (int i=0;i<=E_;i++) goff[i]=off[i];
  }
  __syncthreads();
  if (tid<MAXTILES){
    const int r=tid*128; int e=-1;
    for (int j=0;j<E_;j++) if (r>=off[j] && r<off[j+1]) e=j;
    tile_expert[tid]=e;
  }
  const int lane=tid&63;
  const int e=tid>>6;
  int base=off[e];
  for (int c=0;c<T_/64;c++){
    const int t=c*64+lane;
    const int a0=top_i[2*t], a1=top_i[2*t+1];
    const bool f=(a0==e)||(a1==e);
    const unsigned long long m=__ballot(f);
    if (f){
      const int pos = base + (int)__popcll(m & ((1ull<<lane)-1ull));
      assign_token[pos]=t;
      pos_of[2*t + (a0==e?0:1)] = pos;
    }
    base += (int)__popcll(m);
  }
  for (int r=base+lane; r<off[e+1]; r+=64) assign_token[r]=-1;
  __syncthreads();
  for (int r=off[E_]+tid; r<MAXROWS; r+=512) assign_token[r]=-1;
  // ---- fused load-balance loss ----
  float fc[E_]={0,0,0,0,0,0,0,0}, Ps[E_]={0,0,0,0,0,0,0,0};
  for (int t=tid;t<T_;t+=512){
    const float* pr = probs + (size_t)t*E_;
    const int a0 = top_i[2*t];
    #pragma unroll
    for (int k=0;k<E_;k++){
      Ps[k] += pr[k];
      fc[k] += (a0==k) ? 1.0f : 0.0f;
    }
  }
  #pragma unroll
  for (int k=0;k<E_;k++){
    #pragma unroll
    for (int o=32;o;o>>=1){ fc[k]+=__shfl_xor(fc[k],o); Ps[k]+=__shfl_xor(Ps[k],o); }
  }
  const int wid8 = tid>>6;
  if (lane==0){
    #pragma unroll
    for (int k=0;k<E_;k++){ sf[wid8][k]=fc[k]; sP[wid8][k]=Ps[k]; }
  }
  __syncthreads();
  if (tid==0){
    float loss=0.f;
    #pragma unroll
    for (int k=0;k<E_;k++){
      float fe=0.f, Pe=0.f;
      #pragma unroll
      for (int w=0;w<8;w++){ fe+=sf[w][k]; Pe+=sP[w][k]; }
      loss += (fe/(float)T_)*(Pe/(float)T_);
    }
    loss_out[0] = 0.01f*(float)E_*loss;
  }
}

// grouped bf16 GEMM, BK=32, LDS dbuf + counted vmcnt(4), XCD-chunked 1D grid.
// MODE 2: FFN1 + tanh-GELU, A gathered DIRECTLY from n2b via atok.
// MODE 3: FFN2, dense A. (R14/R18 measured-best configuration.)
template<int MODE>
__global__ void __launch_bounds__(256, 4) gemm_grp_kernel(
    const u16* __restrict__ A, int lda,
    const u16* __restrict__ Bbase, int Kdim, int Nsz, int NT,
    const float* __restrict__ bias,
    const int* __restrict__ tile_expert,
    const int* __restrict__ atok,
    u16* __restrict__ outp)
{
  const int bid = blockIdx.x, nwg = gridDim.x;
  const int fid = (bid & 7)*(nwg>>3) + (bid>>3);
  const int nt = fid % NT, mt = fid / NT;
  const int e = tile_expert[mt];
  if (e<0) return;
  __shared__ __align__(16) u16 Ash[2][128*32], Bsh[2][128*32];
  const int tid=threadIdx.x, wid=tid>>6, lane=tid&63;
  const int wr=wid>>1, wc=wid&1;
  const int r16=lane&15, g4=lane>>4;
  const float* bp = bias + (size_t)e*Nsz;
  const int srow = wid*16 + (lane>>2);
  const int scol = (((lane&3) ^ ((lane>>3)&3)))*8;
  const int sl   = (g4 ^ ((r16>>1)&3))*8;
  const u16* Bg = Bbase + (size_t)e*Nsz*Kdim + (size_t)nt*128*Kdim;
  size_t arow0, arow1;
  if (MODE==2){
    int t0 = atok[mt*128 + srow];      if (t0 < 0) t0 = 0;
    int t1 = atok[mt*128 + 64 + srow]; if (t1 < 0) t1 = 0;
    arow0 = (size_t)t0*lda;
    arow1 = (size_t)t1*lda;
  } else {
    arow0 = (size_t)(mt*128 + srow)*lda;
    arow1 = (size_t)(mt*128 + 64 + srow)*lda;
  }
  f32x4 acc[4][4] = {};
#define GSTAGE(bi, k0) do { \
    glds16(A + arow0 + (k0) + scol, &Ash[bi][(wid*16)*32]); \
    glds16(A + arow1 + (k0) + scol, &Ash[bi][(64 + wid*16)*32]); \
    glds16(Bg + (size_t)(srow)*Kdim      + (k0) + scol, &Bsh[bi][(wid*16)*32]); \
    glds16(Bg + (size_t)(64+srow)*Kdim   + (k0) + scol, &Bsh[bi][(64 + wid*16)*32]); \
  } while(0)
  GSTAGE(0, 0);
  int cur = 0;
  const int NK = Kdim/32;
  for (int t=0; t<NK; ++t){
    if (t+1 < NK){
      GSTAGE(cur^1, (t+1)*32);
      asm volatile("s_waitcnt vmcnt(4)" ::: "memory");
    } else {
      asm volatile("s_waitcnt vmcnt(0)" ::: "memory");
    }
    __syncthreads();
    bf16x8 af[4], bfr[4];
    #pragma unroll
    for (int m=0;m<4;m++) af[m]=ld8(&Ash[cur][(wr*64+m*16+r16)*32 + sl]);
    #pragma unroll
    for (int n=0;n<4;n++) bfr[n]=ld8(&Bsh[cur][(wc*64+n*16+r16)*32 + sl]);
    #pragma unroll
    for (int m=0;m<4;m++){
      #pragma unroll
      for (int n=0;n<4;n++) acc[m][n] = mfma16(af[m], bfr[n], acc[m][n]);
    }
    __syncthreads();
    cur ^= 1;
  }
#undef GSTAGE
  #pragma unroll
  for (int m=0;m<4;m++){
    #pragma unroll
    for (int n=0;n<4;n++){
      #pragma unroll
      for (int r=0;r<4;r++){
        const int grow = mt*128 + wr*64 + m*16 + g4*4 + r;
        const int gcol = nt*128 + wc*64 + n*16 + r16;
        float val = acc[m][n][r] + bp[gcol];
        if (MODE==2){
          const float z = val*(1.0f + 0.044715f*val*val)*2.3021622f;
          val = val / (1.0f + __builtin_amdgcn_exp2f(-z));
        }
        outp[(size_t)grow*Nsz + gcol] = f2bf(val);
      }
    }
  }
}

__global__ void __launch_bounds__(256) combine_kernel(const float* __restrict__ x1,
    const u16* __restrict__ eo, const int* __restrict__ pos_of, const float* __restrict__ cw_w,
    float* __restrict__ out0)
{
  const int t=blockIdx.x, tid=threadIdx.x;
  const int r0=pos_of[2*t], r1=pos_of[2*t+1];
  const float w0=cw_w[2*t], w1=cw_w[2*t+1];
  const u16x4 e0 = reinterpret_cast<const u16x4*>(eo + (size_t)r0*D_)[tid];
  const u16x4 e1 = reinterpret_cast<const u16x4*>(eo + (size_t)r1*D_)[tid];
  const float4 xv = reinterpret_cast<const float4*>(x1 + (size_t)t*D_)[tid];
  float4 o;
  o.x = xv.x + w0*bf2f(e0[0]) + w1*bf2f(e1[0]);
  o.y = xv.y + w0*bf2f(e0[1]) + w1*bf2f(e1[1]);
  o.z = xv.z + w0*bf2f(e0[2]) + w1*bf2f(e1[2]);
  o.w = xv.w + w0*bf2f(e0[3]) + w1*bf2f(e1[3]);
  reinterpret_cast<float4*>(out0 + (size_t)t*D_)[tid] = o;
}

static inline size_t alup(size_t x){ return (x+255)&~(size_t)255; }

extern "C" void kernel_launch(void* const* d_in, const int* in_sizes, int n_in,
                              void* d_out, int out_size, void* d_ws, size_t ws_size,
                              hipStream_t stream) {
  (void)in_sizes; (void)n_in; (void)out_size; (void)ws_size;
  const float* x    = (const float*)d_in[0];
  const float* ipw  = (const float*)d_in[1];
  const float* ipb  = (const float*)d_in[2];
  const float* opw  = (const float*)d_in[3];
  const float* opb  = (const float*)d_in[4];
  const float* ln1g = (const float*)d_in[5];
  const float* ln1b = (const float*)d_in[6];
  const float* ln2g = (const float*)d_in[7];
  const float* ln2b = (const float*)d_in[8];
  const float* gw   = (const float*)d_in[9];
  const float* gb   = (const float*)d_in[10];
  const float* w1   = (const float*)d_in[11];
  const float* b1   = (const float*)d_in[12];
  const float* w2   = (const float*)d_in[13];
  const float* b2   = (const float*)d_in[14];

  float* out0       = (float*)d_out;
  float* loss_out   = out0 + (size_t)T_*D_;
  float* probs_out  = loss_out + 1;
  float* normed_out = probs_out + (size_t)T_*E_;

  char* p = (char*)d_ws;
  auto take = [&](size_t bytes)->void*{ void* r = (void*)p; p += alup(bytes); return r; };

  _Float16* wipf  = (_Float16*)take((size_t)3*D_*D_*2);
  _Float16* wophf = (_Float16*)take((size_t)D_*D_*2);
  _Float16* woplf = (_Float16*)take((size_t)D_*D_*2);
  u16* w1b   = (u16*)take((size_t)E_*FF_*D_*2);
  u16* w2b   = (u16*)take((size_t)E_*D_*FF_*2);
  _Float16* nf16 = (_Float16*)take((size_t)T_*D_*2);
  _Float16* qf  = (_Float16*)take((size_t)T_*D_*2);
  _Float16* kf  = (_Float16*)take((size_t)T_*D_*2);
  _Float16* vtf = (_Float16*)take((size_t)T_*D_*2);
  _Float16* of16 = (_Float16*)take((size_t)T_*D_*2);
  float* x1  = (float*)take((size_t)T_*D_*4);
  u16* n2b   = (u16*)take((size_t)T_*D_*2);
  u16* hbuf  = (u16*)take((size_t)MAXROWS*FF_*2);
  u16* eo    = (u16*)take((size_t)MAXROWS*D_*2);
  int* top_i = (int*)take((size_t)T_*2*4);
  float* cww = (float*)take((size_t)T_*2*4);
  int* posof = (int*)take((size_t)T_*2*4);
  int* goff  = (int*)take((size_t)(E_+1)*4);
  int* texp  = (int*)take((size_t)MAXTILES*4);
  int* atok  = (int*)take((size_t)MAXROWS*4);

  const int n4a = 3*D_*D_/4, n4b = D_*D_/4;

  // ln1 + projection-weight conversion fused (blocks >= T_ do the cvt).
  ln_kernel<1,0><<<T_ + (n4a + n4b + 255)/256, 256, 0, stream>>>(
      x, ln1g, ln1b, normed_out, (u16*)nf16,
      nullptr, nullptr, nullptr, nullptr, nullptr,
      ipw, wipf, opw, wophf, woplf, n4a, n4b);

  qkv_kernel<<<dim3(24*(T_/128)), 256, 0, stream>>>(nf16, wipf, ipb, qf, kf, vtf);

  attn_cvt_kernel<<<ATTNB + CVTB, 512, 0, stream>>>(qf, kf, vtf, of16,
                                                    w1, w1b, w2, w2b, E_*FF_*D_/4);

  gemm3_kernel<<<dim3(8*(T_/128)), 256, 0, stream>>>(
      of16, D_, wophf, woplf, D_, opb, x, x1);

  ln_kernel<2,1><<<T_, 256, 0, stream>>>(x1, ln2g, ln2b, nullptr, n2b,
                                         gw, gb, probs_out, top_i, cww,
                                         nullptr, nullptr, nullptr, nullptr, nullptr, 0, 0);

  scan_kernel<<<1, 512, 0, stream>>>(top_i, goff, texp, atok, posof, probs_out, loss_out);

  gemm_grp_kernel<2><<<dim3((FF_/128)*MAXTILES), 256, 0, stream>>>(n2b, D_, w1b, D_, FF_, FF_/128, b1, texp, atok, hbuf);
  gemm_grp_kernel<3><<<dim3((D_/128)*MAXTILES), 256, 0, stream>>>(hbuf, FF_, w2b, FF_, D_, D_/128, b2, texp, nullptr, eo);

  combine_kernel<<<T_, 256, 0, stream>>>(x1, eo, posof, cww, out0);
}